// Round 3
// baseline (2620.860 us; speedup 1.0000x reference)
//
#include <hip/hip_runtime.h>
#include <cstdint>

// Problem constants (B=2, N=2048, D=1024, H=16, HD=64)
#define NB 2
#define NN 2048
#define ND 1024
#define NH 16
#define NHD 64
#define NHB (NB*NH)   // 32
#define WS_NEEDED (24u * 1024u * 1024u)

#if defined(__has_builtin)
#if __has_builtin(__builtin_amdgcn_sdot4)
#define HAS_SDOT4 1
#endif
#endif

__device__ __forceinline__ int dot4(int a, int b, int acc) {
#if defined(HAS_SDOT4)
  return __builtin_amdgcn_sdot4(a, b, acc, false);
#else
  acc += (int)(int8_t)(a & 255)       * (int)(int8_t)(b & 255);
  acc += (int)(int8_t)((a >> 8) & 255) * (int)(int8_t)((b >> 8) & 255);
  acc += (int)(int8_t)((a >> 16) & 255)* (int)(int8_t)((b >> 16) & 255);
  acc += (int)(int8_t)(a >> 24)        * (int)(int8_t)(b >> 24);
  return acc;
#endif
}

__device__ __forceinline__ int clampq(int v) {
  return min(127, max(-128, v));
}

// fallback if ws_size too small: zero the output (clean diagnostic failure)
__global__ __launch_bounds__(256) void zero_out_k(float4* __restrict__ out) {
  out[blockIdx.x * 256 + threadIdx.x] = float4{0.f, 0.f, 0.f, 0.f};
}

// f32 -> int8 fixed-point quantize: round-half-even(x*32), clamp [-128,127]
__global__ __launch_bounds__(256) void quant_k(const float* __restrict__ in,
                                               int* __restrict__ out, int n4) {
  int i = blockIdx.x * blockDim.x + threadIdx.x;
  if (i >= n4) return;
  float4 f = reinterpret_cast<const float4*>(in)[i];
  int a = clampq((int)rintf(f.x * 32.f));
  int b = clampq((int)rintf(f.y * 32.f));
  int c = clampq((int)rintf(f.z * 32.f));
  int d = clampq((int)rintf(f.w * 32.f));
  out[i] = (a & 255) | ((b & 255) << 8) | ((c & 255) << 16) | (d << 24);
}

// quantize 4 bias vectors (1024 floats each) in one launch: blockIdx.x picks src
__global__ __launch_bounds__(256) void quant_bias_k(const float* __restrict__ b0,
                                                    const float* __restrict__ b1,
                                                    const float* __restrict__ b2,
                                                    const float* __restrict__ b3,
                                                    int* __restrict__ o0,
                                                    int* __restrict__ o1,
                                                    int* __restrict__ o2,
                                                    int* __restrict__ o3) {
  const float* src = blockIdx.x == 0 ? b0 : blockIdx.x == 1 ? b1
                   : blockIdx.x == 2 ? b2 : b3;
  int* dst = blockIdx.x == 0 ? o0 : blockIdx.x == 1 ? o1
           : blockIdx.x == 2 ? o2 : o3;
  int i = threadIdx.x;  // 256 threads x float4 = 1024 floats
  float4 f = reinterpret_cast<const float4*>(src)[i];
  int a = clampq((int)rintf(f.x * 32.f));
  int b = clampq((int)rintf(f.y * 32.f));
  int c = clampq((int)rintf(f.z * 32.f));
  int d = clampq((int)rintf(f.w * 32.f));
  dst[i] = (a & 255) | ((b & 255) << 8) | ((c & 255) << 16) | (d << 24);
}

// out[m][n] = quantize( (x_i8[m]·w_i8[n]/1024 + b/32) * scale ), stored in
// head layout [B*H][N][HD] as int8.
__global__ __launch_bounds__(256) void linq_k(const int8_t* __restrict__ x,
                                              const int8_t* __restrict__ w,
                                              const int8_t* __restrict__ bq,
                                              int8_t* __restrict__ out,
                                              float scale) {
  int n = blockIdx.x * 16 + threadIdx.x;   // 0..1023
  int m = blockIdx.y * 16 + threadIdx.y;   // 0..4095
  const int4* xr = reinterpret_cast<const int4*>(x + (size_t)m * ND);
  const int4* wr = reinterpret_cast<const int4*>(w + (size_t)n * ND);
  int acc = 0;
#pragma unroll 4
  for (int k = 0; k < ND / 16; ++k) {
    int4 a = xr[k], bb = wr[k];
    acc = dot4(a.x, bb.x, acc); acc = dot4(a.y, bb.y, acc);
    acc = dot4(a.z, bb.z, acc); acc = dot4(a.w, bb.w, acc);
  }
  float val = ((float)acc * (1.f / 1024.f) + (float)bq[n] * (1.f / 32.f)) * scale;
  int qv = clampq((int)rintf(val * 32.f));
  int b_ = m >> 11, nr = m & 2047, h = n >> 6, hd = n & 63;
  out[(((size_t)((b_ << 4) + h) << 11) + nr) * NHD + hd] = (int8_t)qv;
}

// Attention: one block = 8 query rows of one (b,h). Scores in registers,
// K staged in LDS (stride-80 rows). Softmax per 32-lane row group.
// quantize(p) == 0 for a whole block -> ctx rows are exactly 0 (algebraic).
__global__ __launch_bounds__(256) void attn_k(const int8_t* __restrict__ Q,
                                              const int8_t* __restrict__ K,
                                              const int8_t* __restrict__ V,
                                              const float* __restrict__ mask,
                                              int8_t* __restrict__ ctx) {
  __shared__ __align__(16) char lds[512 * 80];  // 40 KiB K tile
  __shared__ int s_flag;
  const int t = threadIdx.x;
  const int hb = blockIdx.x;     // 0..31
  const int tileR = blockIdx.y;  // 0..255
  const int r = t >> 5;          // 0..7
  const int lane = t & 31;
  const int row = tileR * 8 + r;
  const int b = hb >> 4;
  const int h = hb & 15;

  if (t == 0) s_flag = 0;

  int q[16];
  {
    const int* q4 = (const int*)(Q + ((size_t)hb * NN + row) * NHD);
#pragma unroll
    for (int i = 0; i < 16; ++i) q[i] = q4[i];
  }
  float s[64];
  const float* mrow = mask + ((size_t)b * NN + row) * NN;
  const int8_t* Kh = K + (size_t)hb * NN * NHD;

#pragma unroll
  for (int tile = 0; tile < 4; ++tile) {
    __syncthreads();  // previous tile fully consumed (and covers s_flag init)
    {
      const int4* src = (const int4*)(Kh + (size_t)tile * 512 * NHD);
#pragma unroll
      for (int i = 0; i < 8; ++i) {
        int idx = t * 8 + i;            // int4 index, 0..2047
        int krow = idx >> 2, k4 = idx & 3;
        *(int4*)(lds + krow * 80 + k4 * 16) = src[idx];
      }
    }
    __syncthreads();
#pragma unroll
    for (int jj = 0; jj < 16; ++jj) {
      int cl = lane + (jj << 5);
      const int* kr = (const int*)(lds + cl * 80);
      int acc = 0;
#pragma unroll
      for (int i = 0; i < 16; ++i) acc = dot4(q[i], kr[i], acc);
      s[tile * 16 + jj] = (float)acc * (1.f / 1024.f) + mrow[(tile << 9) + cl];
    }
  }

  // row max (32 lanes own one row; each holds 64 strided cols)
  float mx = s[0];
#pragma unroll
  for (int i = 1; i < 64; ++i) mx = fmaxf(mx, s[i]);
#pragma unroll
  for (int off = 16; off >= 1; off >>= 1) mx = fmaxf(mx, __shfl_xor(mx, off));

  float sum = 0.f;
#pragma unroll
  for (int i = 0; i < 64; ++i) { s[i] = expf(s[i] - mx); sum += s[i]; }
#pragma unroll
  for (int off = 16; off >= 1; off >>= 1) sum += __shfl_xor(sum, off);

  int any = 0;
#pragma unroll
  for (int i = 0; i < 64; ++i) {
    float p = s[i] / sum;                 // IEEE div, matches ref softmax
    int pi = (int)rintf(p * 32.f);        // RNE, matches jnp.round
    pi = min(127, pi);
    any |= pi;
    s[i] = __int_as_float(pi);
  }
  if (any) s_flag = 1;
  __syncthreads();

  int8_t* crow = ctx + ((size_t)b * NN + row) * ND + h * NHD;
  const int hd0 = lane << 1;
  if (s_flag == 0) {
    // all quantized p are 0 -> ctx rows exactly 0 -> quantize(ctx)=0
    crow[hd0] = 0;
    crow[hd0 + 1] = 0;
  } else {
    // exact integer PV fallback
    int8_t* pl = (int8_t*)lds;
#pragma unroll
    for (int i = 0; i < 64; ++i) {
      int c = ((i >> 4) << 9) + lane + ((i & 15) << 5);
      pl[(r << 11) + c] = (int8_t)__float_as_int(s[i]);
    }
    __syncthreads();
    const int8_t* Vh = V + (size_t)hb * NN * NHD;
    int a0 = 0, a1 = 0;
    for (int c = 0; c < NN; ++c) {
      int pv = pl[(r << 11) + c];
      if (pv) {
        a0 += pv * (int)Vh[(size_t)c * NHD + hd0];
        a1 += pv * (int)Vh[(size_t)c * NHD + hd0 + 1];
      }
    }
    // ctx = a/1024 ; quantize -> rint(ctx*32) = rint(a/32) (exact)
    crow[hd0]     = (int8_t)clampq((int)rintf((float)a0 * (1.f / 32.f)));
    crow[hd0 + 1] = (int8_t)clampq((int)rintf((float)a1 * (1.f / 32.f)));
  }
}

// out[m][n] = ctx_i8[m]·ow_i8[n]/1024 + ob/32  (float32 output)
__global__ __launch_bounds__(256) void oproj_k(const int8_t* __restrict__ x,
                                               const int8_t* __restrict__ w,
                                               const int8_t* __restrict__ bq,
                                               float* __restrict__ out) {
  int n = blockIdx.x * 16 + threadIdx.x;
  int m = blockIdx.y * 16 + threadIdx.y;
  const int4* xr = reinterpret_cast<const int4*>(x + (size_t)m * ND);
  const int4* wr = reinterpret_cast<const int4*>(w + (size_t)n * ND);
  int acc = 0;
#pragma unroll 4
  for (int k = 0; k < ND / 16; ++k) {
    int4 a = xr[k], bb = wr[k];
    acc = dot4(a.x, bb.x, acc); acc = dot4(a.y, bb.y, acc);
    acc = dot4(a.z, bb.z, acc); acc = dot4(a.w, bb.w, acc);
  }
  out[(size_t)m * ND + n] = (float)acc * (1.f / 1024.f) + (float)bq[n] * (1.f / 32.f);
}

extern "C" void kernel_launch(void* const* d_in, const int* in_sizes, int n_in,
                              void* d_out, int out_size, void* d_ws, size_t ws_size,
                              hipStream_t stream) {
  float* out = (float*)d_out;

  // Defensive: if scratch is smaller than we assumed, fail cleanly (zero out)
  // instead of writing OOB and killing the container.
  if (ws_size < (size_t)WS_NEEDED) {
    zero_out_k<<<out_size / 1024, 256, 0, stream>>>((float4*)out);
    return;
  }

  const float* hidden = (const float*)d_in[0];
  const float* mask   = (const float*)d_in[1];
  const float* qw = (const float*)d_in[2];
  const float* qb = (const float*)d_in[3];
  const float* kw = (const float*)d_in[4];
  const float* kb = (const float*)d_in[5];
  const float* vw = (const float*)d_in[6];
  const float* vb = (const float*)d_in[7];
  const float* ow = (const float*)d_in[8];
  const float* ob = (const float*)d_in[9];

  char* ws = (char*)d_ws;
  int8_t* x_i8  = (int8_t*)(ws + 0);          // 4 MiB  [4096][1024]
  int8_t* qw_i8 = (int8_t*)(ws + 4194304);    // 1 MiB
  int8_t* kw_i8 = (int8_t*)(ws + 5242880);    // 1 MiB
  int8_t* vw_i8 = (int8_t*)(ws + 6291456);    // 1 MiB
  int8_t* ow_i8 = (int8_t*)(ws + 7340032);    // 1 MiB
  int8_t* qb_i8 = (int8_t*)(ws + 8388608);    // 1 KiB
  int8_t* kb_i8 = (int8_t*)(ws + 8389632);
  int8_t* vb_i8 = (int8_t*)(ws + 8390656);
  int8_t* ob_i8 = (int8_t*)(ws + 8391680);
  int8_t* Q_i8  = (int8_t*)(ws + 8392704);    // 4 MiB [32][2048][64]
  int8_t* K_i8  = (int8_t*)(ws + 12587008);   // 4 MiB
  int8_t* V_i8  = (int8_t*)(ws + 16781312);   // 4 MiB
  int8_t* c_i8  = (int8_t*)(ws + 20975616);   // 4 MiB [4096][1024]

  // 1) quantize inputs to int8
  quant_k<<<4096, 256, 0, stream>>>(hidden, (int*)x_i8, 1048576);
  quant_k<<<1024, 256, 0, stream>>>(qw, (int*)qw_i8, 262144);
  quant_k<<<1024, 256, 0, stream>>>(kw, (int*)kw_i8, 262144);
  quant_k<<<1024, 256, 0, stream>>>(vw, (int*)vw_i8, 262144);
  quant_k<<<1024, 256, 0, stream>>>(ow, (int*)ow_i8, 262144);
  quant_bias_k<<<4, 256, 0, stream>>>(qb, kb, vb, ob,
                                      (int*)qb_i8, (int*)kb_i8,
                                      (int*)vb_i8, (int*)ob_i8);

  // 2) QKV projections (fused bias + scaling + re-quantize, head layout)
  dim3 gg(64, 256), bb(16, 16);
  linq_k<<<gg, bb, 0, stream>>>(x_i8, qw_i8, qb_i8, Q_i8, 0.125f);  // * HD^-0.5
  linq_k<<<gg, bb, 0, stream>>>(x_i8, kw_i8, kb_i8, K_i8, 1.0f);
  linq_k<<<gg, bb, 0, stream>>>(x_i8, vw_i8, vb_i8, V_i8, 1.0f);

  // 3) attention (scores + softmax + quantized PV)
  attn_k<<<dim3(NHB, NN / 8), 256, 0, stream>>>(Q_i8, K_i8, V_i8, mask, c_i8);

  // 4) output projection -> f32
  oproj_k<<<gg, bb, 0, stream>>>(c_i8, ow_i8, ob_i8, out);
}

// Round 4
// 445.797 us; speedup vs baseline: 5.8790x; 5.8790x over previous
//
#include <hip/hip_runtime.h>
#include <cstdint>

// Problem constants (B=2, N=2048, D=1024, H=16, HD=64)
#define NB 2
#define NN 2048
#define ND 1024
#define NH 16
#define NHD 64
#define NHB (NB*NH)   // 32
#define WS_NEEDED (24u * 1024u * 1024u)

#if defined(__has_builtin)
#if __has_builtin(__builtin_amdgcn_sdot4)
#define HAS_SDOT4 1
#endif
#endif

typedef __attribute__((ext_vector_type(4))) int int32x4;

__device__ __forceinline__ int dot4(int a, int b, int acc) {
#if defined(HAS_SDOT4)
  return __builtin_amdgcn_sdot4(a, b, acc, false);
#else
  acc += (int)(int8_t)(a & 255)       * (int)(int8_t)(b & 255);
  acc += (int)(int8_t)((a >> 8) & 255) * (int)(int8_t)((b >> 8) & 255);
  acc += (int)(int8_t)((a >> 16) & 255)* (int)(int8_t)((b >> 16) & 255);
  acc += (int)(int8_t)(a >> 24)        * (int)(int8_t)(b >> 24);
  return acc;
#endif
}

__device__ __forceinline__ int clampq(int v) {
  return min(127, max(-128, v));
}

// fallback if ws_size too small: zero the output (clean diagnostic failure)
__global__ __launch_bounds__(256) void zero_out_k(float4* __restrict__ out) {
  out[blockIdx.x * 256 + threadIdx.x] = float4{0.f, 0.f, 0.f, 0.f};
}

// f32 -> int8 fixed-point quantize: round-half-even(x*32), clamp [-128,127]
__global__ __launch_bounds__(256) void quant_k(const float* __restrict__ in,
                                               int* __restrict__ out, int n4) {
  int i = blockIdx.x * blockDim.x + threadIdx.x;
  if (i >= n4) return;
  float4 f = reinterpret_cast<const float4*>(in)[i];
  int a = clampq((int)rintf(f.x * 32.f));
  int b = clampq((int)rintf(f.y * 32.f));
  int c = clampq((int)rintf(f.z * 32.f));
  int d = clampq((int)rintf(f.w * 32.f));
  out[i] = (a & 255) | ((b & 255) << 8) | ((c & 255) << 16) | (d << 24);
}

// quantize 4 bias vectors (1024 floats each) in one launch
__global__ __launch_bounds__(256) void quant_bias_k(const float* __restrict__ b0,
                                                    const float* __restrict__ b1,
                                                    const float* __restrict__ b2,
                                                    const float* __restrict__ b3,
                                                    int* __restrict__ o0,
                                                    int* __restrict__ o1,
                                                    int* __restrict__ o2,
                                                    int* __restrict__ o3) {
  const float* src = blockIdx.x == 0 ? b0 : blockIdx.x == 1 ? b1
                   : blockIdx.x == 2 ? b2 : b3;
  int* dst = blockIdx.x == 0 ? o0 : blockIdx.x == 1 ? o1
           : blockIdx.x == 2 ? o2 : o3;
  int i = threadIdx.x;
  float4 f = reinterpret_cast<const float4*>(src)[i];
  int a = clampq((int)rintf(f.x * 32.f));
  int b = clampq((int)rintf(f.y * 32.f));
  int c = clampq((int)rintf(f.z * 32.f));
  int d = clampq((int)rintf(f.w * 32.f));
  dst[i] = (a & 255) | ((b & 255) << 8) | ((c & 255) << 16) | (d << 24);
}

// ---------------------------------------------------------------------------
// MFMA i8 GEMM, m97 structure: C[4096][1024] = X[4096][1024] @ W[1024][1024]^T
// 128x128 tile, BK=64 bytes, 4 waves x (64x64 subtile = 4x4 16x16 frags).
// OPROJ=false: fused (acc/1024 + b/32)*scale -> requantize -> int8 head layout
// OPROJ=true : acc/1024 + b/32 -> f32 row-major
// ---------------------------------------------------------------------------
#define BM 128
#define BN 128
#define BK 64

template <bool OPROJ>
__global__ __launch_bounds__(256) void gemm_i8_k(const int8_t* __restrict__ x,
                                                 const int8_t* __restrict__ w,
                                                 const int8_t* __restrict__ bq,
                                                 int8_t* __restrict__ outq,
                                                 float* __restrict__ outf,
                                                 float scale) {
  __shared__ __align__(16) int8_t lA[BM * BK];  // 8 KiB
  __shared__ __align__(16) int8_t lB[BN * BK];  // 8 KiB
  const int t = threadIdx.x;
  const int wid = t >> 6;        // wave 0..3
  const int lane = t & 63;
  const int wr = wid >> 1, wc = wid & 1;
  const int bm = blockIdx.y * BM;
  const int bn = blockIdx.x * BN;

  // staging map: chunk c covers LDS rows [c*16, c*16+16); lane l -> row c*16+(l>>2), byte (l&3)*16
  const int srow = lane >> 2;
  const int scol = (lane & 3) * 16;
  // fragment map (16x16x64 i8): lane holds row (lane&15), k bytes (lane>>4)*16..+15
  const int frow = lane & 15;
  const int fk = (lane >> 4) * 16;

  int32x4 acc[4][4];
#pragma unroll
  for (int i = 0; i < 4; ++i)
#pragma unroll
    for (int j = 0; j < 4; ++j) acc[i][j] = int32x4{0, 0, 0, 0};

  for (int ks = 0; ks < ND / BK; ++ks) {
    const int k0 = ks * BK;
    __syncthreads();  // previous tile fully consumed
#pragma unroll
    for (int i = 0; i < 2; ++i) {
      const int c = i * 4 + wid;               // chunk 0..7
      const int row = c * 16 + srow;
      const int8_t* ga = x + (size_t)(bm + row) * ND + k0 + scol;
      const int8_t* gb = w + (size_t)(bn + row) * ND + k0 + scol;
      __builtin_amdgcn_global_load_lds(
          (const __attribute__((address_space(1))) void*)ga,
          (__attribute__((address_space(3))) void*)(lA + c * 1024), 16, 0, 0);
      __builtin_amdgcn_global_load_lds(
          (const __attribute__((address_space(1))) void*)gb,
          (__attribute__((address_space(3))) void*)(lB + c * 1024), 16, 0, 0);
    }
    __syncthreads();  // (drains vmcnt per barrier semantics)

    int32x4 af[4], bf[4];
#pragma unroll
    for (int mi = 0; mi < 4; ++mi)
      af[mi] = *(const int32x4*)(lA + (wr * 64 + mi * 16 + frow) * BK + fk);
#pragma unroll
    for (int ni = 0; ni < 4; ++ni)
      bf[ni] = *(const int32x4*)(lB + (wc * 64 + ni * 16 + frow) * BK + fk);
#pragma unroll
    for (int mi = 0; mi < 4; ++mi)
#pragma unroll
      for (int ni = 0; ni < 4; ++ni)
        acc[mi][ni] = __builtin_amdgcn_mfma_i32_16x16x64_i8(af[mi], bf[ni],
                                                            acc[mi][ni], 0, 0, 0);
  }

  // epilogue: C/D map col=lane&15, row=(lane>>4)*4+reg  [m89-verified, dtype-indep]
  const int crow = (lane >> 4) * 4;
  const int ccol = lane & 15;
#pragma unroll
  for (int ni = 0; ni < 4; ++ni) {
    const int n = bn + wc * 64 + ni * 16 + ccol;
    const float bqf = (float)bq[n] * (1.f / 32.f);
    const int h = n >> 6, hd = n & 63;
#pragma unroll
    for (int mi = 0; mi < 4; ++mi) {
#pragma unroll
      for (int r = 0; r < 4; ++r) {
        const int m = bm + wr * 64 + mi * 16 + crow + r;
        const float val = (float)acc[mi][ni][r] * (1.f / 1024.f) + bqf;
        if (OPROJ) {
          outf[(size_t)m * ND + n] = val;
        } else {
          const int qv = clampq((int)rintf(val * scale * 32.f));
          const int b_ = m >> 11, nr = m & 2047;
          outq[(((size_t)((b_ << 4) + h) << 11) + nr) * NHD + hd] = (int8_t)qv;
        }
      }
    }
  }
}

// Attention: one block = 8 query rows of one (b,h). Scores in registers,
// K staged in LDS (stride-80 rows). Softmax per 32-lane row group.
// quantize(p) == 0 for a whole block -> ctx rows are exactly 0 (algebraic).
__global__ __launch_bounds__(256) void attn_k(const int8_t* __restrict__ Q,
                                              const int8_t* __restrict__ K,
                                              const int8_t* __restrict__ V,
                                              const float* __restrict__ mask,
                                              int8_t* __restrict__ ctx) {
  __shared__ __align__(16) char lds[512 * 80];  // 40 KiB K tile
  __shared__ int s_flag;
  const int t = threadIdx.x;
  const int hb = blockIdx.x;     // 0..31
  const int tileR = blockIdx.y;  // 0..255
  const int r = t >> 5;          // 0..7
  const int lane = t & 31;
  const int row = tileR * 8 + r;
  const int b = hb >> 4;
  const int h = hb & 15;

  if (t == 0) s_flag = 0;

  int q[16];
  {
    const int* q4 = (const int*)(Q + ((size_t)hb * NN + row) * NHD);
#pragma unroll
    for (int i = 0; i < 16; ++i) q[i] = q4[i];
  }
  float s[64];
  const float* mrow = mask + ((size_t)b * NN + row) * NN;
  const int8_t* Kh = K + (size_t)hb * NN * NHD;

#pragma unroll
  for (int tile = 0; tile < 4; ++tile) {
    __syncthreads();
    {
      const int4* src = (const int4*)(Kh + (size_t)tile * 512 * NHD);
#pragma unroll
      for (int i = 0; i < 8; ++i) {
        int idx = t * 8 + i;
        int krow = idx >> 2, k4 = idx & 3;
        *(int4*)(lds + krow * 80 + k4 * 16) = src[idx];
      }
    }
    __syncthreads();
#pragma unroll
    for (int jj = 0; jj < 16; ++jj) {
      int cl = lane + (jj << 5);
      const int* kr = (const int*)(lds + cl * 80);
      int acc = 0;
#pragma unroll
      for (int i = 0; i < 16; ++i) acc = dot4(q[i], kr[i], acc);
      s[tile * 16 + jj] = (float)acc * (1.f / 1024.f) + mrow[(tile << 9) + cl];
    }
  }

  float mx = s[0];
#pragma unroll
  for (int i = 1; i < 64; ++i) mx = fmaxf(mx, s[i]);
#pragma unroll
  for (int off = 16; off >= 1; off >>= 1) mx = fmaxf(mx, __shfl_xor(mx, off));

  float sum = 0.f;
#pragma unroll
  for (int i = 0; i < 64; ++i) { s[i] = expf(s[i] - mx); sum += s[i]; }
#pragma unroll
  for (int off = 16; off >= 1; off >>= 1) sum += __shfl_xor(sum, off);

  int any = 0;
#pragma unroll
  for (int i = 0; i < 64; ++i) {
    float p = s[i] / sum;
    int pi = (int)rintf(p * 32.f);
    pi = min(127, pi);
    any |= pi;
    s[i] = __int_as_float(pi);
  }
  if (any) s_flag = 1;
  __syncthreads();

  int8_t* crow = ctx + ((size_t)b * NN + row) * ND + h * NHD;
  const int hd0 = lane << 1;
  if (s_flag == 0) {
    crow[hd0] = 0;
    crow[hd0 + 1] = 0;
  } else {
    int8_t* pl = (int8_t*)lds;
#pragma unroll
    for (int i = 0; i < 64; ++i) {
      int c = ((i >> 4) << 9) + lane + ((i & 15) << 5);
      pl[(r << 11) + c] = (int8_t)__float_as_int(s[i]);
    }
    __syncthreads();
    const int8_t* Vh = V + (size_t)hb * NN * NHD;
    int a0 = 0, a1 = 0;
    for (int c = 0; c < NN; ++c) {
      int pv = pl[(r << 11) + c];
      if (pv) {
        a0 += pv * (int)Vh[(size_t)c * NHD + hd0];
        a1 += pv * (int)Vh[(size_t)c * NHD + hd0 + 1];
      }
    }
    crow[hd0]     = (int8_t)clampq((int)rintf((float)a0 * (1.f / 32.f)));
    crow[hd0 + 1] = (int8_t)clampq((int)rintf((float)a1 * (1.f / 32.f)));
  }
}

extern "C" void kernel_launch(void* const* d_in, const int* in_sizes, int n_in,
                              void* d_out, int out_size, void* d_ws, size_t ws_size,
                              hipStream_t stream) {
  float* out = (float*)d_out;

  if (ws_size < (size_t)WS_NEEDED) {
    zero_out_k<<<out_size / 1024, 256, 0, stream>>>((float4*)out);
    return;
  }

  const float* hidden = (const float*)d_in[0];
  const float* mask   = (const float*)d_in[1];
  const float* qw = (const float*)d_in[2];
  const float* qb = (const float*)d_in[3];
  const float* kw = (const float*)d_in[4];
  const float* kb = (const float*)d_in[5];
  const float* vw = (const float*)d_in[6];
  const float* vb = (const float*)d_in[7];
  const float* ow = (const float*)d_in[8];
  const float* ob = (const float*)d_in[9];

  char* ws = (char*)d_ws;
  int8_t* x_i8  = (int8_t*)(ws + 0);          // 4 MiB  [4096][1024]
  int8_t* qw_i8 = (int8_t*)(ws + 4194304);    // 1 MiB
  int8_t* kw_i8 = (int8_t*)(ws + 5242880);    // 1 MiB
  int8_t* vw_i8 = (int8_t*)(ws + 6291456);    // 1 MiB
  int8_t* ow_i8 = (int8_t*)(ws + 7340032);    // 1 MiB
  int8_t* qb_i8 = (int8_t*)(ws + 8388608);    // 1 KiB
  int8_t* kb_i8 = (int8_t*)(ws + 8389632);
  int8_t* vb_i8 = (int8_t*)(ws + 8390656);
  int8_t* ob_i8 = (int8_t*)(ws + 8391680);
  int8_t* Q_i8  = (int8_t*)(ws + 8392704);    // 4 MiB [32][2048][64]
  int8_t* K_i8  = (int8_t*)(ws + 12587008);   // 4 MiB
  int8_t* V_i8  = (int8_t*)(ws + 16781312);   // 4 MiB
  int8_t* c_i8  = (int8_t*)(ws + 20975616);   // 4 MiB [4096][1024]

  // 1) quantize inputs to int8
  quant_k<<<4096, 256, 0, stream>>>(hidden, (int*)x_i8, 1048576);
  quant_k<<<1024, 256, 0, stream>>>(qw, (int*)qw_i8, 262144);
  quant_k<<<1024, 256, 0, stream>>>(kw, (int*)kw_i8, 262144);
  quant_k<<<1024, 256, 0, stream>>>(vw, (int*)vw_i8, 262144);
  quant_k<<<1024, 256, 0, stream>>>(ow, (int*)ow_i8, 262144);
  quant_bias_k<<<4, 256, 0, stream>>>(qb, kb, vb, ob,
                                      (int*)qb_i8, (int*)kb_i8,
                                      (int*)vb_i8, (int*)ob_i8);

  // 2) QKV projections on MFMA (fused bias + scaling + re-quantize, head layout)
  dim3 gg(NN * NB / BN * 0 + 8, 32);  // grid = (N/BN=8, M/BM=32)
  gemm_i8_k<false><<<gg, 256, 0, stream>>>(x_i8, qw_i8, qb_i8, Q_i8, nullptr, 0.125f);
  gemm_i8_k<false><<<gg, 256, 0, stream>>>(x_i8, kw_i8, kb_i8, K_i8, nullptr, 1.0f);
  gemm_i8_k<false><<<gg, 256, 0, stream>>>(x_i8, vw_i8, vb_i8, V_i8, nullptr, 1.0f);

  // 3) attention (scores + softmax + quantized PV)
  attn_k<<<dim3(NHB, NN / 8), 256, 0, stream>>>(Q_i8, K_i8, V_i8, mask, c_i8);

  // 4) output projection on MFMA -> f32
  gemm_i8_k<true><<<gg, 256, 0, stream>>>(c_i8, ow_i8, ob_i8, nullptr, out, 1.0f);
}

// Round 5
// 223.291 us; speedup vs baseline: 11.7374x; 1.9965x over previous
//
#include <hip/hip_runtime.h>
#include <cstdint>
#include <cfloat>

// Problem constants (B=2, N=2048, D=1024, H=16, HD=64)
#define NB 2
#define NN 2048
#define ND 1024
#define NH 16
#define NHD 64
#define NHB (NB*NH)   // 32
#define WS_NEEDED (24u * 1024u * 1024u)

#if defined(__has_builtin)
#if __has_builtin(__builtin_amdgcn_sdot4)
#define HAS_SDOT4 1
#endif
#endif

typedef __attribute__((ext_vector_type(4))) int int32x4;

__device__ __forceinline__ int dot4(int a, int b, int acc) {
#if defined(HAS_SDOT4)
  return __builtin_amdgcn_sdot4(a, b, acc, false);
#else
  acc += (int)(int8_t)(a & 255)       * (int)(int8_t)(b & 255);
  acc += (int)(int8_t)((a >> 8) & 255) * (int)(int8_t)((b >> 8) & 255);
  acc += (int)(int8_t)((a >> 16) & 255)* (int)(int8_t)((b >> 16) & 255);
  acc += (int)(int8_t)(a >> 24)        * (int)(int8_t)(b >> 24);
  return acc;
#endif
}

__device__ __forceinline__ int clampq(int v) {
  return min(127, max(-128, v));
}

// fallback if ws_size too small: zero the output (clean diagnostic failure)
__global__ __launch_bounds__(256) void zero_out_k(float4* __restrict__ out) {
  out[blockIdx.x * 256 + threadIdx.x] = float4{0.f, 0.f, 0.f, 0.f};
}

// f32 -> int8 fixed-point quantize: round-half-even(x*32), clamp [-128,127]
__global__ __launch_bounds__(256) void quant_k(const float* __restrict__ in,
                                               int* __restrict__ out, int n4) {
  int i = blockIdx.x * blockDim.x + threadIdx.x;
  if (i >= n4) return;
  float4 f = reinterpret_cast<const float4*>(in)[i];
  int a = clampq((int)rintf(f.x * 32.f));
  int b = clampq((int)rintf(f.y * 32.f));
  int c = clampq((int)rintf(f.z * 32.f));
  int d = clampq((int)rintf(f.w * 32.f));
  out[i] = (a & 255) | ((b & 255) << 8) | ((c & 255) << 16) | (d << 24);
}

// quantize 4 bias vectors (1024 floats each) in one launch
__global__ __launch_bounds__(256) void quant_bias_k(const float* __restrict__ b0,
                                                    const float* __restrict__ b1,
                                                    const float* __restrict__ b2,
                                                    const float* __restrict__ b3,
                                                    int* __restrict__ o0,
                                                    int* __restrict__ o1,
                                                    int* __restrict__ o2,
                                                    int* __restrict__ o3) {
  const float* src = blockIdx.x == 0 ? b0 : blockIdx.x == 1 ? b1
                   : blockIdx.x == 2 ? b2 : b3;
  int* dst = blockIdx.x == 0 ? o0 : blockIdx.x == 1 ? o1
           : blockIdx.x == 2 ? o2 : o3;
  int i = threadIdx.x;
  float4 f = reinterpret_cast<const float4*>(src)[i];
  int a = clampq((int)rintf(f.x * 32.f));
  int b = clampq((int)rintf(f.y * 32.f));
  int c = clampq((int)rintf(f.z * 32.f));
  int d = clampq((int)rintf(f.w * 32.f));
  dst[i] = (a & 255) | ((b & 255) << 8) | ((c & 255) << 16) | (d << 24);
}

// per-(b,row): flag=1 if mask row is all zeros (attn can skip mask reads)
__global__ __launch_bounds__(256) void maskchk_k(const float* __restrict__ mask,
                                                 int* __restrict__ flags) {
  __shared__ int red[256];
  const int row = blockIdx.x;      // 0..4095 (b*2048 + r)
  const int t = threadIdx.x;
  const float4* mr = (const float4*)(mask + (size_t)row * NN);
  int nz = 0;
#pragma unroll
  for (int i = 0; i < 2; ++i) {
    float4 f = mr[t * 2 + i];
    nz |= (f.x != 0.f) | (f.y != 0.f) | (f.z != 0.f) | (f.w != 0.f);
  }
  red[t] = nz;
  __syncthreads();
  for (int off = 128; off; off >>= 1) {
    if (t < off) red[t] |= red[t + off];
    __syncthreads();
  }
  if (t == 0) flags[row] = (red[0] == 0);
}

// ---------------------------------------------------------------------------
// MFMA i8 GEMM (m97 structure), verified bit-exact in round 4.
// ---------------------------------------------------------------------------
#define BM 128
#define BN 128
#define BK 64

template <bool OPROJ>
__global__ __launch_bounds__(256) void gemm_i8_k(const int8_t* __restrict__ x,
                                                 const int8_t* __restrict__ w,
                                                 const int8_t* __restrict__ bq,
                                                 int8_t* __restrict__ outq,
                                                 float* __restrict__ outf,
                                                 float scale) {
  __shared__ __align__(16) int8_t lA[BM * BK];
  __shared__ __align__(16) int8_t lB[BN * BK];
  const int t = threadIdx.x;
  const int wid = t >> 6;
  const int lane = t & 63;
  const int wr = wid >> 1, wc = wid & 1;
  const int bm = blockIdx.y * BM;
  const int bn = blockIdx.x * BN;

  const int srow = lane >> 2;
  const int scol = (lane & 3) * 16;
  const int frow = lane & 15;
  const int fk = (lane >> 4) * 16;

  int32x4 acc[4][4];
#pragma unroll
  for (int i = 0; i < 4; ++i)
#pragma unroll
    for (int j = 0; j < 4; ++j) acc[i][j] = int32x4{0, 0, 0, 0};

  for (int ks = 0; ks < ND / BK; ++ks) {
    const int k0 = ks * BK;
    __syncthreads();
#pragma unroll
    for (int i = 0; i < 2; ++i) {
      const int c = i * 4 + wid;
      const int row = c * 16 + srow;
      const int8_t* ga = x + (size_t)(bm + row) * ND + k0 + scol;
      const int8_t* gb = w + (size_t)(bn + row) * ND + k0 + scol;
      __builtin_amdgcn_global_load_lds(
          (const __attribute__((address_space(1))) void*)ga,
          (__attribute__((address_space(3))) void*)(lA + c * 1024), 16, 0, 0);
      __builtin_amdgcn_global_load_lds(
          (const __attribute__((address_space(1))) void*)gb,
          (__attribute__((address_space(3))) void*)(lB + c * 1024), 16, 0, 0);
    }
    __syncthreads();

    int32x4 af[4], bf[4];
#pragma unroll
    for (int mi = 0; mi < 4; ++mi)
      af[mi] = *(const int32x4*)(lA + (wr * 64 + mi * 16 + frow) * BK + fk);
#pragma unroll
    for (int ni = 0; ni < 4; ++ni)
      bf[ni] = *(const int32x4*)(lB + (wc * 64 + ni * 16 + frow) * BK + fk);
#pragma unroll
    for (int mi = 0; mi < 4; ++mi)
#pragma unroll
      for (int ni = 0; ni < 4; ++ni)
        acc[mi][ni] = __builtin_amdgcn_mfma_i32_16x16x64_i8(af[mi], bf[ni],
                                                            acc[mi][ni], 0, 0, 0);
  }

  const int crow = (lane >> 4) * 4;
  const int ccol = lane & 15;
#pragma unroll
  for (int ni = 0; ni < 4; ++ni) {
    const int n = bn + wc * 64 + ni * 16 + ccol;
    const float bqf = (float)bq[n] * (1.f / 32.f);
    const int h = n >> 6, hd = n & 63;
#pragma unroll
    for (int mi = 0; mi < 4; ++mi) {
#pragma unroll
      for (int r = 0; r < 4; ++r) {
        const int m = bm + wr * 64 + mi * 16 + crow + r;
        const float val = (float)acc[mi][ni][r] * (1.f / 1024.f) + bqf;
        if (OPROJ) {
          outf[(size_t)m * ND + n] = val;
        } else {
          const int qv = clampq((int)rintf(val * scale * 32.f));
          const int b_ = m >> 11, nr = m & 2047;
          outq[(((size_t)((b_ << 4) + h) << 11) + nr) * NHD + hd] = (int8_t)qv;
        }
      }
    }
  }
}

// ---------------------------------------------------------------------------
// Attention: block = (b,h) x 32 q-rows. MFMA QK^T (swapped: A=K-tile, B=Q),
// online (max, sum-of-exp) per q-row; all-p-quantize-to-zero decision is
// algebraic (sum_norm >= 96 => rint(32*e/sum)==0 for all e<=1, ref margin 64).
// Dirty rows (rare) take an exact per-row fallback (dot4 + expf + int PV).
// ---------------------------------------------------------------------------
__global__ __launch_bounds__(256) void attn_k(const int8_t* __restrict__ Q,
                                              const int8_t* __restrict__ K,
                                              const int8_t* __restrict__ V,
                                              const float* __restrict__ mask,
                                              const int* __restrict__ flags,
                                              int8_t* __restrict__ ctx) {
  __shared__ float wm[4][32], wsum[4][32];
  __shared__ int s_dirty[32];
  __shared__ int s_nm;
  __shared__ float sfb[NN];     // 8 KiB, fallback only
  __shared__ float fred[256];
  __shared__ int ired[256];
  __shared__ int8_t pq[NN];

  const int t = threadIdx.x;
  const int hb = blockIdx.x, b = hb >> 4, h = hb & 15;
  const int q0 = blockIdx.y * 32;
  const int wid = t >> 6, lane = t & 63;
  const int l15 = lane & 15, l4 = lane >> 4;

  if (t == 0) s_nm = 1;
  __syncthreads();
  if (t < 32 && flags[b * NN + q0 + t] == 0) s_nm = 0;
  __syncthreads();
  const bool nomask = (s_nm != 0);

  const int8_t* Qh = Q + (size_t)hb * NN * NHD;
  const int8_t* Kh = K + (size_t)hb * NN * NHD;

  // loop-invariant Q B-frags (verified 16x16x64 layout: col=l&15, k=(l>>4)*16)
  const int32x4 qb0 = *(const int32x4*)(Qh + (size_t)(q0 + l15) * NHD + l4 * 16);
  const int32x4 qb1 = *(const int32x4*)(Qh + (size_t)(q0 + 16 + l15) * NHD + l4 * 16);

  const float* mr0 = mask + ((size_t)(b * NN + q0 + l15)) * NN;
  const float* mr1 = mr0 + (size_t)16 * NN;

  float m0 = -INFINITY, m1 = -INFINITY, s0 = 0.f, s1 = 0.f;
  const int kwbase = wid * 512;
  for (int kt = 0; kt < 32; ++kt) {
    const int kb = kwbase + kt * 16;
    const int32x4 a = *(const int32x4*)(Kh + (size_t)(kb + l15) * NHD + l4 * 16);
    const int32x4 z4 = {0, 0, 0, 0};
    // D[k][q]: k=(l>>4)*4+reg, q=l&15  (swapped-operand QK^T)
    const int32x4 c0 = __builtin_amdgcn_mfma_i32_16x16x64_i8(a, qb0, z4, 0, 0, 0);
    const int32x4 c1 = __builtin_amdgcn_mfma_i32_16x16x64_i8(a, qb1, z4, 0, 0, 0);
    const int kofs = kb + l4 * 4;
    float sv0[4], sv1[4], tm0 = -INFINITY, tm1 = -INFINITY;
#pragma unroll
    for (int r = 0; r < 4; ++r) {
      float v0 = (float)c0[r] * (1.f / 1024.f) + (nomask ? 0.f : mr0[kofs + r]);
      v0 = fmaxf(v0, -FLT_MAX); sv0[r] = v0; tm0 = fmaxf(tm0, v0);
      float v1 = (float)c1[r] * (1.f / 1024.f) + (nomask ? 0.f : mr1[kofs + r]);
      v1 = fmaxf(v1, -FLT_MAX); sv1[r] = v1; tm1 = fmaxf(tm1, v1);
    }
    const float mn0 = fmaxf(m0, tm0), mn1 = fmaxf(m1, tm1);
    s0 = s0 * __expf(m0 - mn0) + __expf(sv0[0] - mn0) + __expf(sv0[1] - mn0)
       + __expf(sv0[2] - mn0) + __expf(sv0[3] - mn0);
    s1 = s1 * __expf(m1 - mn1) + __expf(sv1[0] - mn1) + __expf(sv1[1] - mn1)
       + __expf(sv1[2] - mn1) + __expf(sv1[3] - mn1);
    m0 = mn0; m1 = mn1;
  }

  // combine lanes sharing the same q (groups {l, l^16, l^32, l^48})
#pragma unroll
  for (int off = 16; off <= 32; off <<= 1) {
    float mo = __shfl_xor(m0, off), so = __shfl_xor(s0, off);
    float mn = fmaxf(m0, mo);
    s0 = s0 * __expf(m0 - mn) + so * __expf(mo - mn); m0 = mn;
    mo = __shfl_xor(m1, off); so = __shfl_xor(s1, off);
    mn = fmaxf(m1, mo);
    s1 = s1 * __expf(m1 - mn) + so * __expf(mo - mn); m1 = mn;
  }
  if (lane < 16) { wm[wid][lane] = m0; wsum[wid][lane] = s0; }
  else if (lane < 32) { wm[wid][lane] = m1; wsum[wid][lane] = s1; }
  __syncthreads();

  if (t < 32) {
    float M = wm[0][t];
#pragma unroll
    for (int w = 1; w < 4; ++w) M = fmaxf(M, wm[w][t]);
    float S = 0.f;
#pragma unroll
    for (int w = 0; w < 4; ++w) S += wsum[w][t] * __expf(wm[w][t] - M);
    s_dirty[t] = (S < 96.f) ? 1 : 0;
  }
  __syncthreads();

  // clean rows: ctx is exactly zero (all quantized p == 0)
  {
    const int rl = t >> 3;
    if (!s_dirty[rl]) {
      int2* p = (int2*)(ctx + ((size_t)(b * NN + q0 + rl)) * ND + h * NHD);
      p[t & 7] = int2{0, 0};
    }
  }

  // dirty rows: exact fallback (block-cooperative, rare)
  for (int rl = 0; rl < 32; ++rl) {
    if (!s_dirty[rl]) continue;
    __syncthreads();
    const int qrow = q0 + rl;
    const int* Qr = (const int*)(Qh + (size_t)qrow * NHD);
    const float* mrow = mask + ((size_t)(b * NN + qrow)) * NN;
    int qreg[16];
#pragma unroll
    for (int i = 0; i < 16; ++i) qreg[i] = Qr[i];
#pragma unroll
    for (int jj = 0; jj < 8; ++jj) {
      const int j = jj * 256 + t;
      const int* Kj = (const int*)(Kh + (size_t)j * NHD);
      int acc = 0;
#pragma unroll
      for (int i = 0; i < 16; ++i) acc = dot4(qreg[i], Kj[i], acc);
      sfb[j] = fmaxf((float)acc * (1.f / 1024.f) + mrow[j], -FLT_MAX);
    }
    __syncthreads();
    float lm = -INFINITY;
#pragma unroll
    for (int jj = 0; jj < 8; ++jj) lm = fmaxf(lm, sfb[jj * 256 + t]);
    fred[t] = lm;
    __syncthreads();
    for (int off = 128; off; off >>= 1) {
      if (t < off) fred[t] = fmaxf(fred[t], fred[t + off]);
      __syncthreads();
    }
    const float M = fred[0];
    __syncthreads();
    float ls = 0.f;
#pragma unroll
    for (int jj = 0; jj < 8; ++jj) {
      const int j = jj * 256 + t;
      const float e = expf(sfb[j] - M);
      sfb[j] = e; ls += e;
    }
    fred[t] = ls;
    __syncthreads();
    for (int off = 128; off; off >>= 1) {
      if (t < off) fred[t] += fred[t + off];
      __syncthreads();
    }
    const float S = fred[0];
#pragma unroll
    for (int jj = 0; jj < 8; ++jj) {
      const int j = jj * 256 + t;
      const int pi = (int)rintf(sfb[j] / S * 32.f);
      pq[j] = (int8_t)min(127, pi);
    }
    __syncthreads();
    const int8_t* Vh = V + (size_t)hb * NN * NHD;
    const int d = t & 63, ch = t >> 6;
    int a = 0;
    for (int j = ch * 512; j < ch * 512 + 512; ++j) {
      const int pv = pq[j];
      if (pv) a += pv * (int)Vh[(size_t)j * NHD + d];
    }
    ired[t] = a;
    __syncthreads();
    if (t < 64) {
      const int tot = ired[t] + ired[t + 64] + ired[t + 128] + ired[t + 192];
      ctx[((size_t)(b * NN + qrow)) * ND + h * NHD + t] =
          (int8_t)clampq((int)rintf((float)tot * (1.f / 32.f)));
    }
    __syncthreads();
  }
}

extern "C" void kernel_launch(void* const* d_in, const int* in_sizes, int n_in,
                              void* d_out, int out_size, void* d_ws, size_t ws_size,
                              hipStream_t stream) {
  float* out = (float*)d_out;

  if (ws_size < (size_t)WS_NEEDED) {
    zero_out_k<<<out_size / 1024, 256, 0, stream>>>((float4*)out);
    return;
  }

  const float* hidden = (const float*)d_in[0];
  const float* mask   = (const float*)d_in[1];
  const float* qw = (const float*)d_in[2];
  const float* qb = (const float*)d_in[3];
  const float* kw = (const float*)d_in[4];
  const float* kb = (const float*)d_in[5];
  const float* vw = (const float*)d_in[6];
  const float* vb = (const float*)d_in[7];
  const float* ow = (const float*)d_in[8];
  const float* ob = (const float*)d_in[9];

  char* ws = (char*)d_ws;
  int8_t* x_i8  = (int8_t*)(ws + 0);          // 4 MiB; reused as mask flags later
  int8_t* qw_i8 = (int8_t*)(ws + 4194304);
  int8_t* kw_i8 = (int8_t*)(ws + 5242880);
  int8_t* vw_i8 = (int8_t*)(ws + 6291456);
  int8_t* ow_i8 = (int8_t*)(ws + 7340032);
  int8_t* qb_i8 = (int8_t*)(ws + 8388608);
  int8_t* kb_i8 = (int8_t*)(ws + 8389632);
  int8_t* vb_i8 = (int8_t*)(ws + 8390656);
  int8_t* ob_i8 = (int8_t*)(ws + 8391680);
  int8_t* Q_i8  = (int8_t*)(ws + 8392704);    // 4 MiB [32][2048][64]
  int8_t* K_i8  = (int8_t*)(ws + 12587008);   // 4 MiB
  int8_t* V_i8  = (int8_t*)(ws + 16781312);   // 4 MiB
  int8_t* c_i8  = (int8_t*)(ws + 20975616);   // 4 MiB [4096][1024]
  int* mflags   = (int*)(ws + 0);             // 16 KiB, aliases x_i8 (dead then)

  // 1) quantize inputs to int8
  quant_k<<<4096, 256, 0, stream>>>(hidden, (int*)x_i8, 1048576);
  quant_k<<<1024, 256, 0, stream>>>(qw, (int*)qw_i8, 262144);
  quant_k<<<1024, 256, 0, stream>>>(kw, (int*)kw_i8, 262144);
  quant_k<<<1024, 256, 0, stream>>>(vw, (int*)vw_i8, 262144);
  quant_k<<<1024, 256, 0, stream>>>(ow, (int*)ow_i8, 262144);
  quant_bias_k<<<4, 256, 0, stream>>>(qb, kb, vb, ob,
                                      (int*)qb_i8, (int*)kb_i8,
                                      (int*)vb_i8, (int*)ob_i8);

  // 2) QKV projections on MFMA
  dim3 gg(8, 32);
  gemm_i8_k<false><<<gg, 256, 0, stream>>>(x_i8, qw_i8, qb_i8, Q_i8, nullptr, 0.125f);
  gemm_i8_k<false><<<gg, 256, 0, stream>>>(x_i8, kw_i8, kb_i8, K_i8, nullptr, 1.0f);
  gemm_i8_k<false><<<gg, 256, 0, stream>>>(x_i8, vw_i8, vb_i8, V_i8, nullptr, 1.0f);

  // 3) mask all-zero precheck (writes over x_i8 region, which is now dead)
  maskchk_k<<<NB * NN, 256, 0, stream>>>(mask, mflags);

  // 4) attention (MFMA QK^T + online sum/max + algebraic zero-PV, exact fallback)
  attn_k<<<dim3(NHB, NN / 32), 256, 0, stream>>>(Q_i8, K_i8, V_i8, mask, mflags, c_i8);

  // 5) output projection on MFMA -> f32
  gemm_i8_k<true><<<gg, 256, 0, stream>>>(c_i8, ow_i8, ob_i8, nullptr, out, 1.0f);
}

// Round 6
// 199.232 us; speedup vs baseline: 13.1548x; 1.1208x over previous
//
#include <hip/hip_runtime.h>
#include <cstdint>
#include <cfloat>
#include <climits>

// Problem constants (B=2, N=2048, D=1024, H=16, HD=64)
#define NB 2
#define NN 2048
#define ND 1024
#define NH 16
#define NHD 64
#define NHB (NB*NH)   // 32
#define WS_NEEDED (24u * 1024u * 1024u)

#if defined(__has_builtin)
#if __has_builtin(__builtin_amdgcn_sdot4)
#define HAS_SDOT4 1
#endif
#endif

typedef __attribute__((ext_vector_type(4))) int int32x4;

__device__ __forceinline__ int dot4(int a, int b, int acc) {
#if defined(HAS_SDOT4)
  return __builtin_amdgcn_sdot4(a, b, acc, false);
#else
  acc += (int)(int8_t)(a & 255)       * (int)(int8_t)(b & 255);
  acc += (int)(int8_t)((a >> 8) & 255) * (int)(int8_t)((b >> 8) & 255);
  acc += (int)(int8_t)((a >> 16) & 255)* (int)(int8_t)((b >> 16) & 255);
  acc += (int)(int8_t)(a >> 24)        * (int)(int8_t)(b >> 24);
  return acc;
#endif
}

__device__ __forceinline__ int clampq(int v) {
  return min(127, max(-128, v));
}

__global__ __launch_bounds__(256) void zero_out_k(float4* __restrict__ out) {
  out[blockIdx.x * 256 + threadIdx.x] = float4{0.f, 0.f, 0.f, 0.f};
}

// f32 -> int8 fixed-point quantize: round-half-even(x*32), clamp [-128,127]
__global__ __launch_bounds__(256) void quant_k(const float* __restrict__ in,
                                               int* __restrict__ out, int n4) {
  int i = blockIdx.x * blockDim.x + threadIdx.x;
  if (i >= n4) return;
  float4 f = reinterpret_cast<const float4*>(in)[i];
  int a = clampq((int)rintf(f.x * 32.f));
  int b = clampq((int)rintf(f.y * 32.f));
  int c = clampq((int)rintf(f.z * 32.f));
  int d = clampq((int)rintf(f.w * 32.f));
  out[i] = (a & 255) | ((b & 255) << 8) | ((c & 255) << 16) | (d << 24);
}

// quantize all 4 weight matrices in one launch (1024 blocks each)
__global__ __launch_bounds__(256) void quant_w_k(const float* __restrict__ w0,
                                                 const float* __restrict__ w1,
                                                 const float* __restrict__ w2,
                                                 const float* __restrict__ w3,
                                                 int* __restrict__ o0,
                                                 int* __restrict__ o1,
                                                 int* __restrict__ o2,
                                                 int* __restrict__ o3) {
  const int which = blockIdx.x >> 10;
  const float* src = which == 0 ? w0 : which == 1 ? w1 : which == 2 ? w2 : w3;
  int* dst = which == 0 ? o0 : which == 1 ? o1 : which == 2 ? o2 : o3;
  const int i = (blockIdx.x & 1023) * 256 + threadIdx.x;
  float4 f = reinterpret_cast<const float4*>(src)[i];
  int a = clampq((int)rintf(f.x * 32.f));
  int b = clampq((int)rintf(f.y * 32.f));
  int c = clampq((int)rintf(f.z * 32.f));
  int d = clampq((int)rintf(f.w * 32.f));
  dst[i] = (a & 255) | ((b & 255) << 8) | ((c & 255) << 16) | (d << 24);
}

// quantize 4 bias vectors (1024 floats each) in one launch
__global__ __launch_bounds__(256) void quant_bias_k(const float* __restrict__ b0,
                                                    const float* __restrict__ b1,
                                                    const float* __restrict__ b2,
                                                    const float* __restrict__ b3,
                                                    int* __restrict__ o0,
                                                    int* __restrict__ o1,
                                                    int* __restrict__ o2,
                                                    int* __restrict__ o3) {
  const float* src = blockIdx.x == 0 ? b0 : blockIdx.x == 1 ? b1
                   : blockIdx.x == 2 ? b2 : b3;
  int* dst = blockIdx.x == 0 ? o0 : blockIdx.x == 1 ? o1
           : blockIdx.x == 2 ? o2 : o3;
  int i = threadIdx.x;
  float4 f = reinterpret_cast<const float4*>(src)[i];
  int a = clampq((int)rintf(f.x * 32.f));
  int b = clampq((int)rintf(f.y * 32.f));
  int c = clampq((int)rintf(f.z * 32.f));
  int d = clampq((int)rintf(f.w * 32.f));
  dst[i] = (a & 255) | ((b & 255) << 8) | ((c & 255) << 16) | (d << 24);
}

// per-(b,row): flag=1 if mask row is all zeros
__global__ __launch_bounds__(256) void maskchk_k(const float* __restrict__ mask,
                                                 int* __restrict__ flags) {
  __shared__ int red[256];
  const int row = blockIdx.x;
  const int t = threadIdx.x;
  const float4* mr = (const float4*)(mask + (size_t)row * NN);
  int nz = 0;
#pragma unroll
  for (int i = 0; i < 2; ++i) {
    float4 f = mr[t * 2 + i];
    nz |= (f.x != 0.f) | (f.y != 0.f) | (f.z != 0.f) | (f.w != 0.f);
  }
  red[t] = nz;
  __syncthreads();
  for (int off = 128; off; off >>= 1) {
    if (t < off) red[t] |= red[t + off];
    __syncthreads();
  }
  if (t == 0) flags[row] = (red[0] == 0);
}

// ---------------------------------------------------------------------------
// MFMA i8 GEMM body (fragment/staging math verified bit-exact rounds 4-5).
// BM=64 for 2x grid parallelism; 4 waves, wave owns 32x64 (acc[2][4]).
// ---------------------------------------------------------------------------
#define BM 64
#define BN 128
#define BK 64

template <bool OPROJ>
__device__ __forceinline__ void gemm_body(const int8_t* __restrict__ x,
                                          const int8_t* __restrict__ w,
                                          const int8_t* __restrict__ bq,
                                          int8_t* __restrict__ outq,
                                          float* __restrict__ outf,
                                          float scale) {
  __shared__ __align__(16) int8_t lA[BM * BK];  // 4 KiB
  __shared__ __align__(16) int8_t lB[BN * BK];  // 8 KiB
  const int t = threadIdx.x;
  const int wid = t >> 6;
  const int lane = t & 63;
  const int wr = wid >> 1, wc = wid & 1;
  const int bm = blockIdx.y * BM;
  const int bn = blockIdx.x * BN;

  const int srow = lane >> 2;          // staging: lane -> row srow, byte scol
  const int scol = (lane & 3) * 16;    // (lane*16 == srow*64 + scol)
  const int frow = lane & 15;          // fragment: row lane&15, k (lane>>4)*16
  const int fk = (lane >> 4) * 16;

  int32x4 acc[2][4];
#pragma unroll
  for (int i = 0; i < 2; ++i)
#pragma unroll
    for (int j = 0; j < 4; ++j) acc[i][j] = int32x4{0, 0, 0, 0};

  for (int ks = 0; ks < ND / BK; ++ks) {
    const int k0 = ks * BK;
    __syncthreads();
    {  // A chunks 0..3 (one per wave)
      const int row = wid * 16 + srow;
      __builtin_amdgcn_global_load_lds(
          (const __attribute__((address_space(1))) void*)(x + (size_t)(bm + row) * ND + k0 + scol),
          (__attribute__((address_space(3))) void*)(lA + wid * 1024), 16, 0, 0);
    }
    {  // B chunks 0..3
      const int row = wid * 16 + srow;
      __builtin_amdgcn_global_load_lds(
          (const __attribute__((address_space(1))) void*)(w + (size_t)(bn + row) * ND + k0 + scol),
          (__attribute__((address_space(3))) void*)(lB + wid * 1024), 16, 0, 0);
    }
    {  // B chunks 4..7
      const int row = (wid + 4) * 16 + srow;
      __builtin_amdgcn_global_load_lds(
          (const __attribute__((address_space(1))) void*)(w + (size_t)(bn + row) * ND + k0 + scol),
          (__attribute__((address_space(3))) void*)(lB + (wid + 4) * 1024), 16, 0, 0);
    }
    __syncthreads();

    int32x4 af[2], bf[4];
#pragma unroll
    for (int mi = 0; mi < 2; ++mi)
      af[mi] = *(const int32x4*)(lA + (wr * 32 + mi * 16 + frow) * BK + fk);
#pragma unroll
    for (int ni = 0; ni < 4; ++ni)
      bf[ni] = *(const int32x4*)(lB + (wc * 64 + ni * 16 + frow) * BK + fk);
#pragma unroll
    for (int mi = 0; mi < 2; ++mi)
#pragma unroll
      for (int ni = 0; ni < 4; ++ni)
        acc[mi][ni] = __builtin_amdgcn_mfma_i32_16x16x64_i8(af[mi], bf[ni],
                                                            acc[mi][ni], 0, 0, 0);
  }

  const int crow = (lane >> 4) * 4;   // C/D map: col=lane&15, row=(lane>>4)*4+reg
  const int ccol = lane & 15;
#pragma unroll
  for (int ni = 0; ni < 4; ++ni) {
    const int n = bn + wc * 64 + ni * 16 + ccol;
    const float bqf = (float)bq[n] * (1.f / 32.f);
    const int h = n >> 6, hd = n & 63;
#pragma unroll
    for (int mi = 0; mi < 2; ++mi) {
#pragma unroll
      for (int r = 0; r < 4; ++r) {
        const int m = bm + wr * 32 + mi * 16 + crow + r;
        const float val = (float)acc[mi][ni][r] * (1.f / 1024.f) + bqf;
        if (OPROJ) {
          outf[(size_t)m * ND + n] = val;
        } else {
          const int qv = clampq((int)rintf(val * scale * 32.f));
          const int b_ = m >> 11, nr = m & 2047;
          outq[(((size_t)((b_ << 4) + h) << 11) + nr) * NHD + hd] = (int8_t)qv;
        }
      }
    }
  }
}

// fused Q/K/V projection: blockIdx.z selects the weight/bias/output/scale
__global__ __launch_bounds__(256) void gemm_qkv_k(const int8_t* __restrict__ x,
                                                  const int8_t* __restrict__ wq,
                                                  const int8_t* __restrict__ wk,
                                                  const int8_t* __restrict__ wv,
                                                  const int8_t* __restrict__ bqq,
                                                  const int8_t* __restrict__ bqk,
                                                  const int8_t* __restrict__ bqv,
                                                  int8_t* __restrict__ oq,
                                                  int8_t* __restrict__ ok,
                                                  int8_t* __restrict__ ov) {
  const int z = blockIdx.z;
  const int8_t* w = z == 0 ? wq : z == 1 ? wk : wv;
  const int8_t* bq = z == 0 ? bqq : z == 1 ? bqk : bqv;
  int8_t* out = z == 0 ? oq : z == 1 ? ok : ov;
  const float scale = z == 0 ? 0.125f : 1.0f;
  gemm_body<false>(x, w, bq, out, nullptr, scale);
}

__global__ __launch_bounds__(256) void gemm_o_k(const int8_t* __restrict__ x,
                                                const int8_t* __restrict__ w,
                                                const int8_t* __restrict__ bq,
                                                float* __restrict__ out) {
  gemm_body<true>(x, w, bq, nullptr, out, 1.0f);
}

// ---------------------------------------------------------------------------
// Attention: block = (b,h) x 32 q-rows. Two-pass: (1) true row max M (integer
// max on raw MFMA accs when mask==0 — monotone <=> float max); (2) sum of
// exp(s-M), one __expf per score (s-M exact in f32). Clean decision S>=96 vs
// exact threshold 64 (max exp = 1). Dirty rows: exact fallback.
// ---------------------------------------------------------------------------
__global__ __launch_bounds__(256) void attn_k(const int8_t* __restrict__ Q,
                                              const int8_t* __restrict__ K,
                                              const int8_t* __restrict__ V,
                                              const float* __restrict__ mask,
                                              const int* __restrict__ flags,
                                              int8_t* __restrict__ ctx) {
  __shared__ float wred[4][32];
  __shared__ float sM[32];
  __shared__ int s_dirty[32];
  __shared__ int s_nm;
  __shared__ float sfb[NN];
  __shared__ float fred[256];
  __shared__ int ired[256];
  __shared__ int8_t pq[NN];

  const int t = threadIdx.x;
  const int hb = blockIdx.x, b = hb >> 4, h = hb & 15;
  const int q0 = blockIdx.y * 32;
  const int wid = t >> 6, lane = t & 63;
  const int l15 = lane & 15, l4 = lane >> 4;

  if (t == 0) s_nm = 1;
  __syncthreads();
  if (t < 32 && flags[b * NN + q0 + t] == 0) s_nm = 0;
  __syncthreads();
  const bool nomask = (s_nm != 0);

  const int8_t* Qh = Q + (size_t)hb * NN * NHD;
  const int8_t* Kh = K + (size_t)hb * NN * NHD;

  // loop-invariant Q B-frags (verified layout: col=l&15, k=(l>>4)*16)
  const int32x4 qb0 = *(const int32x4*)(Qh + (size_t)(q0 + l15) * NHD + l4 * 16);
  const int32x4 qb1 = *(const int32x4*)(Qh + (size_t)(q0 + 16 + l15) * NHD + l4 * 16);

  const float* mr0 = mask + ((size_t)(b * NN + q0 + l15)) * NN;
  const float* mr1 = mr0 + (size_t)16 * NN;
  const int kwbase = wid * 512;
  const int32x4 z4 = {0, 0, 0, 0};

  // ---- pass 1: row max ----
  float m0, m1;
  if (nomask) {
    int im0 = INT_MIN, im1 = INT_MIN;
    for (int kt = 0; kt < 32; ++kt) {
      const int kb = kwbase + kt * 16;
      const int32x4 a = *(const int32x4*)(Kh + (size_t)(kb + l15) * NHD + l4 * 16);
      const int32x4 c0 = __builtin_amdgcn_mfma_i32_16x16x64_i8(a, qb0, z4, 0, 0, 0);
      const int32x4 c1 = __builtin_amdgcn_mfma_i32_16x16x64_i8(a, qb1, z4, 0, 0, 0);
#pragma unroll
      for (int r = 0; r < 4; ++r) {
        im0 = max(im0, c0[r]);
        im1 = max(im1, c1[r]);
      }
    }
    m0 = (float)im0 * (1.f / 1024.f);
    m1 = (float)im1 * (1.f / 1024.f);
  } else {
    m0 = -FLT_MAX; m1 = -FLT_MAX;
    for (int kt = 0; kt < 32; ++kt) {
      const int kb = kwbase + kt * 16;
      const int32x4 a = *(const int32x4*)(Kh + (size_t)(kb + l15) * NHD + l4 * 16);
      const int32x4 c0 = __builtin_amdgcn_mfma_i32_16x16x64_i8(a, qb0, z4, 0, 0, 0);
      const int32x4 c1 = __builtin_amdgcn_mfma_i32_16x16x64_i8(a, qb1, z4, 0, 0, 0);
      const int kofs = kb + l4 * 4;
#pragma unroll
      for (int r = 0; r < 4; ++r) {
        m0 = fmaxf(m0, fmaxf((float)c0[r] * (1.f / 1024.f) + mr0[kofs + r], -FLT_MAX));
        m1 = fmaxf(m1, fmaxf((float)c1[r] * (1.f / 1024.f) + mr1[kofs + r], -FLT_MAX));
      }
    }
  }
#pragma unroll
  for (int off = 16; off <= 32; off <<= 1) {
    m0 = fmaxf(m0, __shfl_xor(m0, off));
    m1 = fmaxf(m1, __shfl_xor(m1, off));
  }
  if (lane < 16) wred[wid][lane] = m0;
  else if (lane < 32) wred[wid][lane] = m1;
  __syncthreads();
  if (t < 32) {
    float M = wred[0][t];
#pragma unroll
    for (int w2 = 1; w2 < 4; ++w2) M = fmaxf(M, wred[w2][t]);
    sM[t] = M;
  }
  __syncthreads();
  const float M0 = sM[l15], M1 = sM[16 + l15];

  // ---- pass 2: sum of exp(s - M) ----
  float s0 = 0.f, s1 = 0.f;
  if (nomask) {
    for (int kt = 0; kt < 32; ++kt) {
      const int kb = kwbase + kt * 16;
      const int32x4 a = *(const int32x4*)(Kh + (size_t)(kb + l15) * NHD + l4 * 16);
      const int32x4 c0 = __builtin_amdgcn_mfma_i32_16x16x64_i8(a, qb0, z4, 0, 0, 0);
      const int32x4 c1 = __builtin_amdgcn_mfma_i32_16x16x64_i8(a, qb1, z4, 0, 0, 0);
#pragma unroll
      for (int r = 0; r < 4; ++r) {
        s0 += __expf(fmaf((float)c0[r], 1.f / 1024.f, -M0));  // exact arg
        s1 += __expf(fmaf((float)c1[r], 1.f / 1024.f, -M1));
      }
    }
  } else {
    for (int kt = 0; kt < 32; ++kt) {
      const int kb = kwbase + kt * 16;
      const int32x4 a = *(const int32x4*)(Kh + (size_t)(kb + l15) * NHD + l4 * 16);
      const int32x4 c0 = __builtin_amdgcn_mfma_i32_16x16x64_i8(a, qb0, z4, 0, 0, 0);
      const int32x4 c1 = __builtin_amdgcn_mfma_i32_16x16x64_i8(a, qb1, z4, 0, 0, 0);
      const int kofs = kb + l4 * 4;
#pragma unroll
      for (int r = 0; r < 4; ++r) {
        float v0 = fmaxf((float)c0[r] * (1.f / 1024.f) + mr0[kofs + r], -FLT_MAX);
        float v1 = fmaxf((float)c1[r] * (1.f / 1024.f) + mr1[kofs + r], -FLT_MAX);
        s0 += __expf(v0 - M0);
        s1 += __expf(v1 - M1);
      }
    }
  }
#pragma unroll
  for (int off = 16; off <= 32; off <<= 1) {
    s0 += __shfl_xor(s0, off);
    s1 += __shfl_xor(s1, off);
  }
  if (lane < 16) wred[wid][lane] = s0;
  else if (lane < 32) wred[wid][lane] = s1;
  __syncthreads();
  if (t < 32) {
    const float S = wred[0][t] + wred[1][t] + wred[2][t] + wred[3][t];
    s_dirty[t] = (S < 96.f) ? 1 : 0;
  }
  __syncthreads();

  // clean rows: ctx exactly zero
  {
    const int rl = t >> 3;
    if (!s_dirty[rl]) {
      int2* p = (int2*)(ctx + ((size_t)(b * NN + q0 + rl)) * ND + h * NHD);
      p[t & 7] = int2{0, 0};
    }
  }

  // dirty rows: exact fallback (rare)
  for (int rl = 0; rl < 32; ++rl) {
    if (!s_dirty[rl]) continue;
    __syncthreads();
    const int qrow = q0 + rl;
    const int* Qr = (const int*)(Qh + (size_t)qrow * NHD);
    const float* mrow = mask + ((size_t)(b * NN + qrow)) * NN;
    int qreg[16];
#pragma unroll
    for (int i = 0; i < 16; ++i) qreg[i] = Qr[i];
#pragma unroll
    for (int jj = 0; jj < 8; ++jj) {
      const int j = jj * 256 + t;
      const int* Kj = (const int*)(Kh + (size_t)j * NHD);
      int acc = 0;
#pragma unroll
      for (int i = 0; i < 16; ++i) acc = dot4(qreg[i], Kj[i], acc);
      sfb[j] = fmaxf((float)acc * (1.f / 1024.f) + mrow[j], -FLT_MAX);
    }
    __syncthreads();
    float lm = -INFINITY;
#pragma unroll
    for (int jj = 0; jj < 8; ++jj) lm = fmaxf(lm, sfb[jj * 256 + t]);
    fred[t] = lm;
    __syncthreads();
    for (int off = 128; off; off >>= 1) {
      if (t < off) fred[t] = fmaxf(fred[t], fred[t + off]);
      __syncthreads();
    }
    const float M = fred[0];
    __syncthreads();
    float ls = 0.f;
#pragma unroll
    for (int jj = 0; jj < 8; ++jj) {
      const int j = jj * 256 + t;
      const float e = expf(sfb[j] - M);
      sfb[j] = e; ls += e;
    }
    fred[t] = ls;
    __syncthreads();
    for (int off = 128; off; off >>= 1) {
      if (t < off) fred[t] += fred[t + off];
      __syncthreads();
    }
    const float S = fred[0];
#pragma unroll
    for (int jj = 0; jj < 8; ++jj) {
      const int j = jj * 256 + t;
      const int pi = (int)rintf(sfb[j] / S * 32.f);
      pq[j] = (int8_t)min(127, pi);
    }
    __syncthreads();
    const int8_t* Vh = V + (size_t)hb * NN * NHD;
    const int d = t & 63, ch = t >> 6;
    int a = 0;
    for (int j = ch * 512; j < ch * 512 + 512; ++j) {
      const int pv = pq[j];
      if (pv) a += pv * (int)Vh[(size_t)j * NHD + d];
    }
    ired[t] = a;
    __syncthreads();
    if (t < 64) {
      const int tot = ired[t] + ired[t + 64] + ired[t + 128] + ired[t + 192];
      ctx[((size_t)(b * NN + qrow)) * ND + h * NHD + t] =
          (int8_t)clampq((int)rintf((float)tot * (1.f / 32.f)));
    }
    __syncthreads();
  }
}

extern "C" void kernel_launch(void* const* d_in, const int* in_sizes, int n_in,
                              void* d_out, int out_size, void* d_ws, size_t ws_size,
                              hipStream_t stream) {
  float* out = (float*)d_out;

  if (ws_size < (size_t)WS_NEEDED) {
    zero_out_k<<<out_size / 1024, 256, 0, stream>>>((float4*)out);
    return;
  }

  const float* hidden = (const float*)d_in[0];
  const float* mask   = (const float*)d_in[1];
  const float* qw = (const float*)d_in[2];
  const float* qb = (const float*)d_in[3];
  const float* kw = (const float*)d_in[4];
  const float* kb = (const float*)d_in[5];
  const float* vw = (const float*)d_in[6];
  const float* vb = (const float*)d_in[7];
  const float* ow = (const float*)d_in[8];
  const float* ob = (const float*)d_in[9];

  char* ws = (char*)d_ws;
  int8_t* x_i8  = (int8_t*)(ws + 0);          // 4 MiB; reused as mask flags later
  int8_t* qw_i8 = (int8_t*)(ws + 4194304);
  int8_t* kw_i8 = (int8_t*)(ws + 5242880);
  int8_t* vw_i8 = (int8_t*)(ws + 6291456);
  int8_t* ow_i8 = (int8_t*)(ws + 7340032);
  int8_t* qb_i8 = (int8_t*)(ws + 8388608);
  int8_t* kb_i8 = (int8_t*)(ws + 8389632);
  int8_t* vb_i8 = (int8_t*)(ws + 8390656);
  int8_t* ob_i8 = (int8_t*)(ws + 8391680);
  int8_t* Q_i8  = (int8_t*)(ws + 8392704);    // 4 MiB [32][2048][64]
  int8_t* K_i8  = (int8_t*)(ws + 12587008);   // 4 MiB
  int8_t* V_i8  = (int8_t*)(ws + 16781312);   // 4 MiB
  int8_t* c_i8  = (int8_t*)(ws + 20975616);   // 4 MiB [4096][1024]
  int* mflags   = (int*)(ws + 0);             // aliases x_i8 (dead after QKV)

  // 1) quantize inputs
  quant_k<<<4096, 256, 0, stream>>>(hidden, (int*)x_i8, 1048576);
  quant_w_k<<<4096, 256, 0, stream>>>(qw, kw, vw, ow, (int*)qw_i8, (int*)kw_i8,
                                      (int*)vw_i8, (int*)ow_i8);
  quant_bias_k<<<4, 256, 0, stream>>>(qb, kb, vb, ob,
                                      (int*)qb_i8, (int*)kb_i8,
                                      (int*)vb_i8, (int*)ob_i8);

  // 2) fused QKV projection (grid.z picks head)
  gemm_qkv_k<<<dim3(ND / BN, NB * NN / BM, 3), 256, 0, stream>>>(
      x_i8, qw_i8, kw_i8, vw_i8, qb_i8, kb_i8, vb_i8, Q_i8, K_i8, V_i8);

  // 3) mask all-zero precheck (overwrites x_i8 region, now dead)
  maskchk_k<<<NB * NN, 256, 0, stream>>>(mask, mflags);

  // 4) attention
  attn_k<<<dim3(NHB, NN / 32), 256, 0, stream>>>(Q_i8, K_i8, V_i8, mask, mflags, c_i8);

  // 5) output projection -> f32
  gemm_o_k<<<dim3(ND / BN, NB * NN / BM), 256, 0, stream>>>(c_i8, ow_i8, ob_i8, out);
}

// Round 8
// 184.159 us; speedup vs baseline: 14.2315x; 1.0818x over previous
//
#include <hip/hip_runtime.h>
#include <cstdint>
#include <cfloat>
#include <climits>

// Problem constants (B=2, N=2048, D=1024, H=16, HD=64)
#define NB 2
#define NN 2048
#define ND 1024
#define NH 16
#define NHD 64
#define NHB (NB*NH)   // 32
#define WS_NEEDED 25169920u   // exact footprint (proven available rounds 3-6)

#if defined(__has_builtin)
#if __has_builtin(__builtin_amdgcn_sdot4)
#define HAS_SDOT4 1
#endif
#if __has_builtin(__builtin_amdgcn_exp2f)
#define EXP2F(x) __builtin_amdgcn_exp2f(x)
#else
#define EXP2F(x) exp2f(x)
#endif
#else
#define EXP2F(x) exp2f(x)
#endif

// log2(e)/1024: maps raw int32 QK accs to exp2 argument
#define C2 0.0014088819735243784f

typedef __attribute__((ext_vector_type(4))) int int32x4;

__device__ __forceinline__ int dot4(int a, int b, int acc) {
#if defined(HAS_SDOT4)
  return __builtin_amdgcn_sdot4(a, b, acc, false);
#else
  acc += (int)(int8_t)(a & 255)       * (int)(int8_t)(b & 255);
  acc += (int)(int8_t)((a >> 8) & 255) * (int)(int8_t)((b >> 8) & 255);
  acc += (int)(int8_t)((a >> 16) & 255)* (int)(int8_t)((b >> 16) & 255);
  acc += (int)(int8_t)(a >> 24)        * (int)(int8_t)(b >> 24);
  return acc;
#endif
}

__device__ __forceinline__ int clampq(int v) {
  return min(127, max(-128, v));
}

__global__ __launch_bounds__(256) void zero_out_k(float4* __restrict__ out) {
  out[blockIdx.x * 256 + threadIdx.x] = float4{0.f, 0.f, 0.f, 0.f};
}

__device__ __forceinline__ int quant4(float4 f) {
  int a = clampq((int)rintf(f.x * 32.f));
  int b = clampq((int)rintf(f.y * 32.f));
  int c = clampq((int)rintf(f.z * 32.f));
  int d = clampq((int)rintf(f.w * 32.f));
  return (a & 255) | ((b & 255) << 8) | ((c & 255) << 16) | (d << 24);
}

// one launch quantizes hidden (blocks 0..4095), 4 weights (4096..8191),
// 4 biases (8192..8195)
__global__ __launch_bounds__(256) void quant_all_k(
    const float* __restrict__ hidden, const float* __restrict__ qw,
    const float* __restrict__ kw, const float* __restrict__ vw,
    const float* __restrict__ ow, const float* __restrict__ qb,
    const float* __restrict__ kb, const float* __restrict__ vb,
    const float* __restrict__ ob, int* __restrict__ xo, int* __restrict__ qwo,
    int* __restrict__ kwo, int* __restrict__ vwo, int* __restrict__ owo,
    int* __restrict__ qbo, int* __restrict__ kbo, int* __restrict__ vbo,
    int* __restrict__ obo) {
  const int bid = blockIdx.x;
  if (bid < 4096) {
    const int i = bid * 256 + threadIdx.x;
    xo[i] = quant4(reinterpret_cast<const float4*>(hidden)[i]);
  } else if (bid < 8192) {
    const int wb = bid - 4096;
    const int which = wb >> 10;
    const float* src = which == 0 ? qw : which == 1 ? kw : which == 2 ? vw : ow;
    int* dst = which == 0 ? qwo : which == 1 ? kwo : which == 2 ? vwo : owo;
    const int i = (wb & 1023) * 256 + threadIdx.x;
    dst[i] = quant4(reinterpret_cast<const float4*>(src)[i]);
  } else {
    const int which = bid - 8192;
    const float* src = which == 0 ? qb : which == 1 ? kb : which == 2 ? vb : ob;
    int* dst = which == 0 ? qbo : which == 1 ? kbo : which == 2 ? vbo : obo;
    const int i = threadIdx.x;
    dst[i] = quant4(reinterpret_cast<const float4*>(src)[i]);
  }
}

// per-(b,row): flag=1 if mask row is all zeros
__global__ __launch_bounds__(256) void maskchk_k(const float* __restrict__ mask,
                                                 int* __restrict__ flags) {
  __shared__ int red[256];
  const int row = blockIdx.x;
  const int t = threadIdx.x;
  const float4* mr = (const float4*)(mask + (size_t)row * NN);
  int nz = 0;
#pragma unroll
  for (int i = 0; i < 2; ++i) {
    float4 f = mr[t * 2 + i];
    nz |= (f.x != 0.f) | (f.y != 0.f) | (f.z != 0.f) | (f.w != 0.f);
  }
  red[t] = nz;
  __syncthreads();
  for (int off = 128; off; off >>= 1) {
    if (t < off) red[t] |= red[t + off];
    __syncthreads();
  }
  if (t == 0) flags[row] = (red[0] == 0);
}

// ---------------------------------------------------------------------------
// MFMA i8 GEMM, double-buffered 2-phase K-loop (T3-minimum):
//   stage(buf0); barrier; loop{ stage(next); ds_read(cur); MFMA; barrier }
// Fragment/staging/C-D maps verified bit-exact rounds 4-6.
// ---------------------------------------------------------------------------
#define BM 64
#define BN 128
#define BK 64

template <bool OPROJ>
__device__ __forceinline__ void gemm_body(const int8_t* __restrict__ x,
                                          const int8_t* __restrict__ w,
                                          const int8_t* __restrict__ bq,
                                          int8_t* __restrict__ outq,
                                          float* __restrict__ outf,
                                          float scale) {
  __shared__ __align__(16) int8_t lA[2][BM * BK];  // 2 x 4 KiB
  __shared__ __align__(16) int8_t lB[2][BN * BK];  // 2 x 8 KiB
  const int t = threadIdx.x;
  const int wid = t >> 6;
  const int lane = t & 63;
  const int wr = wid >> 1, wc = wid & 1;
  const int bm = blockIdx.y * BM;
  const int bn = blockIdx.x * BN;

  const int srow = lane >> 2;          // staging: lane -> row srow, byte scol
  const int scol = (lane & 3) * 16;    // (lane*16 == srow*64 + scol)
  const int frow = lane & 15;          // fragment: row lane&15, k (lane>>4)*16
  const int fk = (lane >> 4) * 16;

  const int8_t* gxa = x + (size_t)(bm + wid * 16 + srow) * ND + scol;
  const int8_t* gwb0 = w + (size_t)(bn + wid * 16 + srow) * ND + scol;
  const int8_t* gwb1 = w + (size_t)(bn + (wid + 4) * 16 + srow) * ND + scol;

#define STAGE(buf, ks)                                                          \
  do {                                                                          \
    const int k0_ = (ks) * BK;                                                  \
    __builtin_amdgcn_global_load_lds(                                           \
        (const __attribute__((address_space(1))) void*)(gxa + k0_),             \
        (__attribute__((address_space(3))) void*)(lA[buf] + wid * 1024), 16, 0, 0); \
    __builtin_amdgcn_global_load_lds(                                           \
        (const __attribute__((address_space(1))) void*)(gwb0 + k0_),            \
        (__attribute__((address_space(3))) void*)(lB[buf] + wid * 1024), 16, 0, 0); \
    __builtin_amdgcn_global_load_lds(                                           \
        (const __attribute__((address_space(1))) void*)(gwb1 + k0_),            \
        (__attribute__((address_space(3))) void*)(lB[buf] + (wid + 4) * 1024), 16, 0, 0); \
  } while (0)

  int32x4 acc[2][4];
#pragma unroll
  for (int i = 0; i < 2; ++i)
#pragma unroll
    for (int j = 0; j < 4; ++j) acc[i][j] = int32x4{0, 0, 0, 0};

  STAGE(0, 0);
  __syncthreads();  // compiler drains vmcnt(0) before barrier: buf0 ready

  for (int ks = 0; ks < ND / BK; ++ks) {
    const int cur = ks & 1;
    if (ks + 1 < ND / BK) STAGE(cur ^ 1, ks + 1);  // loads fly under compute

    int32x4 af[2], bf[4];
#pragma unroll
    for (int mi = 0; mi < 2; ++mi)
      af[mi] = *(const int32x4*)(lA[cur] + (wr * 32 + mi * 16 + frow) * BK + fk);
#pragma unroll
    for (int ni = 0; ni < 4; ++ni)
      bf[ni] = *(const int32x4*)(lB[cur] + (wc * 64 + ni * 16 + frow) * BK + fk);
#pragma unroll
    for (int mi = 0; mi < 2; ++mi)
#pragma unroll
      for (int ni = 0; ni < 4; ++ni)
        acc[mi][ni] = __builtin_amdgcn_mfma_i32_16x16x64_i8(af[mi], bf[ni],
                                                            acc[mi][ni], 0, 0, 0);
    __syncthreads();  // drains next-stage loads; seals cur for reuse
  }
#undef STAGE

  const int crow = (lane >> 4) * 4;   // C/D map: col=lane&15, row=(lane>>4)*4+reg
  const int ccol = lane & 15;
#pragma unroll
  for (int ni = 0; ni < 4; ++ni) {
    const int n = bn + wc * 64 + ni * 16 + ccol;
    const float bqf = (float)bq[n] * (1.f / 32.f);
    const int h = n >> 6, hd = n & 63;
#pragma unroll
    for (int mi = 0; mi < 2; ++mi) {
#pragma unroll
      for (int r = 0; r < 4; ++r) {
        const int m = bm + wr * 32 + mi * 16 + crow + r;
        const float val = (float)acc[mi][ni][r] * (1.f / 1024.f) + bqf;
        if (OPROJ) {
          outf[(size_t)m * ND + n] = val;
        } else {
          const int qv = clampq((int)rintf(val * scale * 32.f));
          const int b_ = m >> 11, nr = m & 2047;
          outq[(((size_t)((b_ << 4) + h) << 11) + nr) * NHD + hd] = (int8_t)qv;
        }
      }
    }
  }
}

__global__ __launch_bounds__(256) void gemm_qkv_k(const int8_t* __restrict__ x,
                                                  const int8_t* __restrict__ wq,
                                                  const int8_t* __restrict__ wk,
                                                  const int8_t* __restrict__ wv,
                                                  const int8_t* __restrict__ bqq,
                                                  const int8_t* __restrict__ bqk,
                                                  const int8_t* __restrict__ bqv,
                                                  int8_t* __restrict__ oq,
                                                  int8_t* __restrict__ ok,
                                                  int8_t* __restrict__ ov) {
  const int z = blockIdx.z;
  const int8_t* w = z == 0 ? wq : z == 1 ? wk : wv;
  const int8_t* bq = z == 0 ? bqq : z == 1 ? bqk : bqv;
  int8_t* out = z == 0 ? oq : z == 1 ? ok : ov;
  const float scale = z == 0 ? 0.125f : 1.0f;
  gemm_body<false>(x, w, bq, out, nullptr, scale);
}

__global__ __launch_bounds__(256) void gemm_o_k(const int8_t* __restrict__ x,
                                                const int8_t* __restrict__ w,
                                                const int8_t* __restrict__ bq,
                                                float* __restrict__ out) {
  gemm_body<true>(x, w, bq, nullptr, out, 1.0f);
}

// ---------------------------------------------------------------------------
// Attention. nomask (the common case): ONE fused pass per 32 q-rows:
// integer row-max M + S2 = sum of 2^(acc*C2) (no max subtraction; scores tiny).
// Clean iff S2 * 2^(-M*C2) >= 96 (true cutoff 64; 1.5x margin). Guards:
// |M| > 61440 -> dirty; NaN/inf -> dirty; underflow of small terms only
// underestimates S2 (conservative toward dirty). Dirty rows: exact fallback.
// masked case: two-pass float path (round-6 code).
// ---------------------------------------------------------------------------
__global__ __launch_bounds__(256) void attn_k(const int8_t* __restrict__ Q,
                                              const int8_t* __restrict__ K,
                                              const int8_t* __restrict__ V,
                                              const float* __restrict__ mask,
                                              const int* __restrict__ flags,
                                              int8_t* __restrict__ ctx) {
  __shared__ float wredf[4][32];
  __shared__ int wredi[4][32];
  __shared__ float sM[32];
  __shared__ int s_dirty[32];
  __shared__ int s_nm;
  __shared__ float sfb[NN];
  __shared__ float fred[256];
  __shared__ int ired[256];
  __shared__ int8_t pq[NN];

  const int t = threadIdx.x;
  const int hb = blockIdx.x, b = hb >> 4, h = hb & 15;
  const int q0 = blockIdx.y * 32;
  const int wid = t >> 6, lane = t & 63;
  const int l15 = lane & 15, l4 = lane >> 4;

  if (t == 0) s_nm = 1;
  __syncthreads();
  if (t < 32 && flags[b * NN + q0 + t] == 0) s_nm = 0;
  __syncthreads();
  const bool nomask = (s_nm != 0);

  const int8_t* Qh = Q + (size_t)hb * NN * NHD;
  const int8_t* Kh = K + (size_t)hb * NN * NHD;

  // loop-invariant Q B-frags (verified layout: col=l&15, k=(l>>4)*16)
  const int32x4 qb0 = *(const int32x4*)(Qh + (size_t)(q0 + l15) * NHD + l4 * 16);
  const int32x4 qb1 = *(const int32x4*)(Qh + (size_t)(q0 + 16 + l15) * NHD + l4 * 16);

  const float* mr0 = mask + ((size_t)(b * NN + q0 + l15)) * NN;
  const float* mr1 = mr0 + (size_t)16 * NN;
  const int kwbase = wid * 512;
  const int32x4 z4 = {0, 0, 0, 0};

  if (nomask) {
    // ---- single fused pass: int max + sum of 2^(acc*C2) ----
    int im0 = INT_MIN, im1 = INT_MIN;
    float s0 = 0.f, s1 = 0.f;
    for (int kt = 0; kt < 32; ++kt) {
      const int kb = kwbase + kt * 16;
      const int32x4 a = *(const int32x4*)(Kh + (size_t)(kb + l15) * NHD + l4 * 16);
      const int32x4 c0 = __builtin_amdgcn_mfma_i32_16x16x64_i8(a, qb0, z4, 0, 0, 0);
      const int32x4 c1 = __builtin_amdgcn_mfma_i32_16x16x64_i8(a, qb1, z4, 0, 0, 0);
#pragma unroll
      for (int r = 0; r < 4; ++r) {
        im0 = max(im0, c0[r]);
        s0 += EXP2F((float)c0[r] * C2);
        im1 = max(im1, c1[r]);
        s1 += EXP2F((float)c1[r] * C2);
      }
    }
#pragma unroll
    for (int off = 16; off <= 32; off <<= 1) {
      im0 = max(im0, __shfl_xor(im0, off)); s0 += __shfl_xor(s0, off);
      im1 = max(im1, __shfl_xor(im1, off)); s1 += __shfl_xor(s1, off);
    }
    if (lane < 16) { wredi[wid][lane] = im0; wredf[wid][lane] = s0; }
    else if (lane < 32) { wredi[wid][lane] = im1; wredf[wid][lane] = s1; }
    __syncthreads();
    if (t < 32) {
      int M = wredi[0][t];
      float S = wredf[0][t];
#pragma unroll
      for (int w2 = 1; w2 < 4; ++w2) {
        M = max(M, wredi[w2][t]);
        S += wredf[w2][t];
      }
      float lb = (M > 61440 || M < -61440) ? 0.f
                 : S * EXP2F(-(float)M * C2);
      s_dirty[t] = (lb >= 96.f) ? 0 : 1;   // NaN -> dirty
    }
    __syncthreads();
  } else {
    // ---- masked: two-pass float path (exact decision inputs) ----
    float m0 = -FLT_MAX, m1 = -FLT_MAX;
    for (int kt = 0; kt < 32; ++kt) {
      const int kb = kwbase + kt * 16;
      const int32x4 a = *(const int32x4*)(Kh + (size_t)(kb + l15) * NHD + l4 * 16);
      const int32x4 c0 = __builtin_amdgcn_mfma_i32_16x16x64_i8(a, qb0, z4, 0, 0, 0);
      const int32x4 c1 = __builtin_amdgcn_mfma_i32_16x16x64_i8(a, qb1, z4, 0, 0, 0);
      const int kofs = kb + l4 * 4;
#pragma unroll
      for (int r = 0; r < 4; ++r) {
        m0 = fmaxf(m0, fmaxf((float)c0[r] * (1.f / 1024.f) + mr0[kofs + r], -FLT_MAX));
        m1 = fmaxf(m1, fmaxf((float)c1[r] * (1.f / 1024.f) + mr1[kofs + r], -FLT_MAX));
      }
    }
#pragma unroll
    for (int off = 16; off <= 32; off <<= 1) {
      m0 = fmaxf(m0, __shfl_xor(m0, off));
      m1 = fmaxf(m1, __shfl_xor(m1, off));
    }
    if (lane < 16) wredf[wid][lane] = m0;
    else if (lane < 32) wredf[wid][lane] = m1;
    __syncthreads();
    if (t < 32) {
      float M = wredf[0][t];
#pragma unroll
      for (int w2 = 1; w2 < 4; ++w2) M = fmaxf(M, wredf[w2][t]);
      sM[t] = M;
    }
    __syncthreads();
    const float M0 = sM[l15], M1 = sM[16 + l15];
    float s0 = 0.f, s1 = 0.f;
    for (int kt = 0; kt < 32; ++kt) {
      const int kb = kwbase + kt * 16;
      const int32x4 a = *(const int32x4*)(Kh + (size_t)(kb + l15) * NHD + l4 * 16);
      const int32x4 c0 = __builtin_amdgcn_mfma_i32_16x16x64_i8(a, qb0, z4, 0, 0, 0);
      const int32x4 c1 = __builtin_amdgcn_mfma_i32_16x16x64_i8(a, qb1, z4, 0, 0, 0);
      const int kofs = kb + l4 * 4;
#pragma unroll
      for (int r = 0; r < 4; ++r) {
        float v0 = fmaxf((float)c0[r] * (1.f / 1024.f) + mr0[kofs + r], -FLT_MAX);
        float v1 = fmaxf((float)c1[r] * (1.f / 1024.f) + mr1[kofs + r], -FLT_MAX);
        s0 += __expf(v0 - M0);
        s1 += __expf(v1 - M1);
      }
    }
#pragma unroll
    for (int off = 16; off <= 32; off <<= 1) {
      s0 += __shfl_xor(s0, off);
      s1 += __shfl_xor(s1, off);
    }
    if (lane < 16) wredf[wid][lane] = s0;
    else if (lane < 32) wredf[wid][lane] = s1;
    __syncthreads();
    if (t < 32) {
      const float S = wredf[0][t] + wredf[1][t] + wredf[2][t] + wredf[3][t];
      s_dirty[t] = (S >= 96.f) ? 0 : 1;
    }
    __syncthreads();
  }

  // clean rows: ctx exactly zero
  {
    const int rl = t >> 3;
    if (!s_dirty[rl]) {
      int2* p = (int2*)(ctx + ((size_t)(b * NN + q0 + rl)) * ND + h * NHD);
      p[t & 7] = int2{0, 0};
    }
  }

  // dirty rows: exact fallback (rare; fully honest path)
  for (int rl = 0; rl < 32; ++rl) {
    if (!s_dirty[rl]) continue;
    __syncthreads();
    const int qrow = q0 + rl;
    const int* Qr = (const int*)(Qh + (size_t)qrow * NHD);
    const float* mrow = mask + ((size_t)(b * NN + qrow)) * NN;
    int qreg[16];
#pragma unroll
    for (int i = 0; i < 16; ++i) qreg[i] = Qr[i];
#pragma unroll
    for (int jj = 0; jj < 8; ++jj) {
      const int j = jj * 256 + t;
      const int* Kj = (const int*)(Kh + (size_t)j * NHD);
      int acc = 0;
#pragma unroll
      for (int i = 0; i < 16; ++i) acc = dot4(qreg[i], Kj[i], acc);
      sfb[j] = fmaxf((float)acc * (1.f / 1024.f) + mrow[j], -FLT_MAX);
    }
    __syncthreads();
    float lm = -INFINITY;
#pragma unroll
    for (int jj = 0; jj < 8; ++jj) lm = fmaxf(lm, sfb[jj * 256 + t]);
    fred[t] = lm;
    __syncthreads();
    for (int off = 128; off; off >>= 1) {
      if (t < off) fred[t] = fmaxf(fred[t], fred[t + off]);
      __syncthreads();
    }
    const float M = fred[0];
    __syncthreads();
    float ls = 0.f;
#pragma unroll
    for (int jj = 0; jj < 8; ++jj) {
      const int j = jj * 256 + t;
      const float e = expf(sfb[j] - M);
      sfb[j] = e; ls += e;
    }
    fred[t] = ls;
    __syncthreads();
    for (int off = 128; off; off >>= 1) {
      if (t < off) fred[t] += fred[t + off];
      __syncthreads();
    }
    const float S = fred[0];
#pragma unroll
    for (int jj = 0; jj < 8; ++jj) {
      const int j = jj * 256 + t;
      const int pi = (int)rintf(sfb[j] / S * 32.f);
      pq[j] = (int8_t)min(127, pi);
    }
    __syncthreads();
    const int8_t* Vh = V + (size_t)hb * NN * NHD;
    const int d = t & 63, ch = t >> 6;
    int a = 0;
    for (int j = ch * 512; j < ch * 512 + 512; ++j) {
      const int pv = pq[j];
      if (pv) a += pv * (int)Vh[(size_t)j * NHD + d];
    }
    ired[t] = a;
    __syncthreads();
    if (t < 64) {
      const int tot = ired[t] + ired[t + 64] + ired[t + 128] + ired[t + 192];
      ctx[((size_t)(b * NN + qrow)) * ND + h * NHD + t] =
          (int8_t)clampq((int)rintf((float)tot * (1.f / 32.f)));
    }
    __syncthreads();
  }
}

extern "C" void kernel_launch(void* const* d_in, const int* in_sizes, int n_in,
                              void* d_out, int out_size, void* d_ws, size_t ws_size,
                              hipStream_t stream) {
  float* out = (float*)d_out;

  if (ws_size < (size_t)WS_NEEDED) {
    zero_out_k<<<out_size / 1024, 256, 0, stream>>>((float4*)out);
    return;
  }

  const float* hidden = (const float*)d_in[0];
  const float* mask   = (const float*)d_in[1];
  const float* qw = (const float*)d_in[2];
  const float* qb = (const float*)d_in[3];
  const float* kw = (const float*)d_in[4];
  const float* kb = (const float*)d_in[5];
  const float* vw = (const float*)d_in[6];
  const float* vb = (const float*)d_in[7];
  const float* ow = (const float*)d_in[8];
  const float* ob = (const float*)d_in[9];

  char* ws = (char*)d_ws;
  int8_t* x_i8  = (int8_t*)(ws + 0);          // 4 MiB; reused as mask flags later
  int8_t* qw_i8 = (int8_t*)(ws + 4194304);
  int8_t* kw_i8 = (int8_t*)(ws + 5242880);
  int8_t* vw_i8 = (int8_t*)(ws + 6291456);
  int8_t* ow_i8 = (int8_t*)(ws + 7340032);
  int8_t* qb_i8 = (int8_t*)(ws + 8388608);
  int8_t* kb_i8 = (int8_t*)(ws + 8389632);
  int8_t* vb_i8 = (int8_t*)(ws + 8390656);
  int8_t* ob_i8 = (int8_t*)(ws + 8391680);
  int8_t* Q_i8  = (int8_t*)(ws + 8392704);    // 4 MiB [32][2048][64]
  int8_t* K_i8  = (int8_t*)(ws + 12587008);   // 4 MiB
  int8_t* V_i8  = (int8_t*)(ws + 16781312);   // 4 MiB
  int8_t* c_i8  = (int8_t*)(ws + 20975616);   // 4 MiB [4096][1024]
  int* mflags   = (int*)(ws + 0);             // aliases x_i8 (dead after QKV)

  // 1) quantize everything in one launch
  quant_all_k<<<8196, 256, 0, stream>>>(hidden, qw, kw, vw, ow, qb, kb, vb, ob,
                                        (int*)x_i8, (int*)qw_i8, (int*)kw_i8,
                                        (int*)vw_i8, (int*)ow_i8, (int*)qb_i8,
                                        (int*)kb_i8, (int*)vb_i8, (int*)ob_i8);

  // 2) fused QKV projection (grid.z picks head), dbuf 2-phase K-loop
  gemm_qkv_k<<<dim3(ND / BN, NB * NN / BM, 3), 256, 0, stream>>>(
      x_i8, qw_i8, kw_i8, vw_i8, qb_i8, kb_i8, vb_i8, Q_i8, K_i8, V_i8);

  // 3) mask all-zero precheck (overwrites x_i8 region, now dead)
  maskchk_k<<<NB * NN, 256, 0, stream>>>(mask, mflags);

  // 4) attention (fused single-pass certificate + exact fallback)
  attn_k<<<dim3(NHB, NN / 32), 256, 0, stream>>>(Q_i8, K_i8, V_i8, mask, mflags, c_i8);

  // 5) output projection -> f32
  gemm_o_k<<<dim3(ND / BN, NB * NN / BM), 256, 0, stream>>>(c_i8, ow_i8, ob_i8, out);
}

// Round 9
// 183.805 us; speedup vs baseline: 14.2589x; 1.0019x over previous
//
#include <hip/hip_runtime.h>
#include <cstdint>
#include <cfloat>
#include <climits>

// Problem constants (B=2, N=2048, D=1024, H=16, HD=64)
#define NB 2
#define NN 2048
#define ND 1024
#define NH 16
#define NHD 64
#define NHB (NB*NH)   // 32
#define WS_NEEDED 25186304u   // 25169920 + 16 KiB mask flags (ws is 256 MiB)

#if defined(__has_builtin)
#if __has_builtin(__builtin_amdgcn_sdot4)
#define HAS_SDOT4 1
#endif
#if __has_builtin(__builtin_amdgcn_exp2f)
#define EXP2F(x) __builtin_amdgcn_exp2f(x)
#else
#define EXP2F(x) exp2f(x)
#endif
#else
#define EXP2F(x) exp2f(x)
#endif

// log2(e)/1024: maps raw int32 QK accs to exp2 argument
#define C2 0.0014088819735243784f

typedef __attribute__((ext_vector_type(4))) int int32x4;

__device__ __forceinline__ int dot4(int a, int b, int acc) {
#if defined(HAS_SDOT4)
  return __builtin_amdgcn_sdot4(a, b, acc, false);
#else
  acc += (int)(int8_t)(a & 255)       * (int)(int8_t)(b & 255);
  acc += (int)(int8_t)((a >> 8) & 255) * (int)(int8_t)((b >> 8) & 255);
  acc += (int)(int8_t)((a >> 16) & 255)* (int)(int8_t)((b >> 16) & 255);
  acc += (int)(int8_t)(a >> 24)        * (int)(int8_t)(b >> 24);
  return acc;
#endif
}

__device__ __forceinline__ int clampq(int v) {
  return min(127, max(-128, v));
}

__global__ __launch_bounds__(256) void zero_out_k(float4* __restrict__ out) {
  out[blockIdx.x * 256 + threadIdx.x] = float4{0.f, 0.f, 0.f, 0.f};
}

__device__ __forceinline__ int quant4(float4 f) {
  int a = clampq((int)rintf(f.x * 32.f));
  int b = clampq((int)rintf(f.y * 32.f));
  int c = clampq((int)rintf(f.z * 32.f));
  int d = clampq((int)rintf(f.w * 32.f));
  return (a & 255) | ((b & 255) << 8) | ((c & 255) << 16) | (d << 24);
}

// one launch: hidden (blocks 0..4095), weights (4096..8191), biases
// (8192..8195), mask all-zero row flags (8196..12291)
__global__ __launch_bounds__(256) void quant_all_k(
    const float* __restrict__ hidden, const float* __restrict__ qw,
    const float* __restrict__ kw, const float* __restrict__ vw,
    const float* __restrict__ ow, const float* __restrict__ qb,
    const float* __restrict__ kb, const float* __restrict__ vb,
    const float* __restrict__ ob, const float* __restrict__ mask,
    int* __restrict__ xo, int* __restrict__ qwo, int* __restrict__ kwo,
    int* __restrict__ vwo, int* __restrict__ owo, int* __restrict__ qbo,
    int* __restrict__ kbo, int* __restrict__ vbo, int* __restrict__ obo,
    int* __restrict__ flags) {
  __shared__ int red[256];
  const int bid = blockIdx.x;
  const int t = threadIdx.x;
  if (bid < 4096) {
    const int i = bid * 256 + t;
    xo[i] = quant4(reinterpret_cast<const float4*>(hidden)[i]);
  } else if (bid < 8192) {
    const int wb = bid - 4096;
    const int which = wb >> 10;
    const float* src = which == 0 ? qw : which == 1 ? kw : which == 2 ? vw : ow;
    int* dst = which == 0 ? qwo : which == 1 ? kwo : which == 2 ? vwo : owo;
    const int i = (wb & 1023) * 256 + t;
    dst[i] = quant4(reinterpret_cast<const float4*>(src)[i]);
  } else if (bid < 8196) {
    const int which = bid - 8192;
    const float* src = which == 0 ? qb : which == 1 ? kb : which == 2 ? vb : ob;
    int* dst = which == 0 ? qbo : which == 1 ? kbo : which == 2 ? vbo : obo;
    dst[t] = quant4(reinterpret_cast<const float4*>(src)[t]);
  } else {
    const int row = bid - 8196;   // 0..4095 = b*2048 + r
    const float4* mr = (const float4*)(mask + (size_t)row * NN);
    int nz = 0;
#pragma unroll
    for (int i = 0; i < 2; ++i) {
      float4 f = mr[t * 2 + i];
      nz |= (f.x != 0.f) | (f.y != 0.f) | (f.z != 0.f) | (f.w != 0.f);
    }
    red[t] = nz;
    __syncthreads();
    for (int off = 128; off; off >>= 1) {
      if (t < off) red[t] |= red[t + off];
      __syncthreads();
    }
    if (t == 0) flags[row] = (red[0] == 0);
  }
}

// ---------------------------------------------------------------------------
// MFMA i8 GEMM, double-buffered 2-phase K-loop (verified bit-exact round 8).
// ---------------------------------------------------------------------------
#define BM 64
#define BN 128
#define BK 64

template <bool OPROJ>
__device__ __forceinline__ void gemm_body(const int8_t* __restrict__ x,
                                          const int8_t* __restrict__ w,
                                          const int8_t* __restrict__ bq,
                                          int8_t* __restrict__ outq,
                                          float* __restrict__ outf,
                                          float scale) {
  __shared__ __align__(16) int8_t lA[2][BM * BK];  // 2 x 4 KiB
  __shared__ __align__(16) int8_t lB[2][BN * BK];  // 2 x 8 KiB
  const int t = threadIdx.x;
  const int wid = t >> 6;
  const int lane = t & 63;
  const int wr = wid >> 1, wc = wid & 1;
  const int bm = blockIdx.y * BM;
  const int bn = blockIdx.x * BN;

  const int srow = lane >> 2;          // staging: lane -> row srow, byte scol
  const int scol = (lane & 3) * 16;    // (lane*16 == srow*64 + scol)
  const int frow = lane & 15;          // fragment: row lane&15, k (lane>>4)*16
  const int fk = (lane >> 4) * 16;

  const int8_t* gxa = x + (size_t)(bm + wid * 16 + srow) * ND + scol;
  const int8_t* gwb0 = w + (size_t)(bn + wid * 16 + srow) * ND + scol;
  const int8_t* gwb1 = w + (size_t)(bn + (wid + 4) * 16 + srow) * ND + scol;

#define STAGE(buf, ks)                                                          \
  do {                                                                          \
    const int k0_ = (ks) * BK;                                                  \
    __builtin_amdgcn_global_load_lds(                                           \
        (const __attribute__((address_space(1))) void*)(gxa + k0_),             \
        (__attribute__((address_space(3))) void*)(lA[buf] + wid * 1024), 16, 0, 0); \
    __builtin_amdgcn_global_load_lds(                                           \
        (const __attribute__((address_space(1))) void*)(gwb0 + k0_),            \
        (__attribute__((address_space(3))) void*)(lB[buf] + wid * 1024), 16, 0, 0); \
    __builtin_amdgcn_global_load_lds(                                           \
        (const __attribute__((address_space(1))) void*)(gwb1 + k0_),            \
        (__attribute__((address_space(3))) void*)(lB[buf] + (wid + 4) * 1024), 16, 0, 0); \
  } while (0)

  int32x4 acc[2][4];
#pragma unroll
  for (int i = 0; i < 2; ++i)
#pragma unroll
    for (int j = 0; j < 4; ++j) acc[i][j] = int32x4{0, 0, 0, 0};

  STAGE(0, 0);
  __syncthreads();  // compiler drains vmcnt(0) before barrier: buf0 ready

  for (int ks = 0; ks < ND / BK; ++ks) {
    const int cur = ks & 1;
    if (ks + 1 < ND / BK) STAGE(cur ^ 1, ks + 1);  // loads fly under compute

    int32x4 af[2], bf[4];
#pragma unroll
    for (int mi = 0; mi < 2; ++mi)
      af[mi] = *(const int32x4*)(lA[cur] + (wr * 32 + mi * 16 + frow) * BK + fk);
#pragma unroll
    for (int ni = 0; ni < 4; ++ni)
      bf[ni] = *(const int32x4*)(lB[cur] + (wc * 64 + ni * 16 + frow) * BK + fk);
#pragma unroll
    for (int mi = 0; mi < 2; ++mi)
#pragma unroll
      for (int ni = 0; ni < 4; ++ni)
        acc[mi][ni] = __builtin_amdgcn_mfma_i32_16x16x64_i8(af[mi], bf[ni],
                                                            acc[mi][ni], 0, 0, 0);
    __syncthreads();  // drains next-stage loads; seals cur for reuse
  }
#undef STAGE

  const int crow = (lane >> 4) * 4;   // C/D map: col=lane&15, row=(lane>>4)*4+reg
  const int ccol = lane & 15;
#pragma unroll
  for (int ni = 0; ni < 4; ++ni) {
    const int n = bn + wc * 64 + ni * 16 + ccol;
    const float bqf = (float)bq[n] * (1.f / 32.f);
    const int h = n >> 6, hd = n & 63;
#pragma unroll
    for (int mi = 0; mi < 2; ++mi) {
#pragma unroll
      for (int r = 0; r < 4; ++r) {
        const int m = bm + wr * 32 + mi * 16 + crow + r;
        const float val = (float)acc[mi][ni][r] * (1.f / 1024.f) + bqf;
        if (OPROJ) {
          outf[(size_t)m * ND + n] = val;
        } else {
          const int qv = clampq((int)rintf(val * scale * 32.f));
          const int b_ = m >> 11, nr = m & 2047;
          outq[(((size_t)((b_ << 4) + h) << 11) + nr) * NHD + hd] = (int8_t)qv;
        }
      }
    }
  }
}

__global__ __launch_bounds__(256) void gemm_qkv_k(const int8_t* __restrict__ x,
                                                  const int8_t* __restrict__ wq,
                                                  const int8_t* __restrict__ wk,
                                                  const int8_t* __restrict__ wv,
                                                  const int8_t* __restrict__ bqq,
                                                  const int8_t* __restrict__ bqk,
                                                  const int8_t* __restrict__ bqv,
                                                  int8_t* __restrict__ oq,
                                                  int8_t* __restrict__ ok,
                                                  int8_t* __restrict__ ov) {
  const int z = blockIdx.z;
  const int8_t* w = z == 0 ? wq : z == 1 ? wk : wv;
  const int8_t* bq = z == 0 ? bqq : z == 1 ? bqk : bqv;
  int8_t* out = z == 0 ? oq : z == 1 ? ok : ov;
  const float scale = z == 0 ? 0.125f : 1.0f;
  gemm_body<false>(x, w, bq, out, nullptr, scale);
}

__global__ __launch_bounds__(256) void gemm_o_k(const int8_t* __restrict__ x,
                                                const int8_t* __restrict__ w,
                                                const int8_t* __restrict__ bq,
                                                float* __restrict__ out) {
  gemm_body<true>(x, w, bq, nullptr, out, 1.0f);
}

// ---------------------------------------------------------------------------
// Attention: block = (b,h) x 64 q-rows (4 Q-frags per K-load; K-frag
// prefetched one iter ahead). nomask: single fused pass, int row-max M +
// S2 = sum 2^(acc*C2); clean iff S2*2^(-M*C2) >= 96 (true cutoff 64).
// Guards: |M|>61440 -> dirty (checked before S2 is used, so inf-overflow of
// S2 can't fake clean); underflow/NaN -> dirty. Dirty rows: exact fallback.
// ---------------------------------------------------------------------------
__global__ __launch_bounds__(256) void attn_k(const int8_t* __restrict__ Q,
                                              const int8_t* __restrict__ K,
                                              const int8_t* __restrict__ V,
                                              const float* __restrict__ mask,
                                              const int* __restrict__ flags,
                                              int8_t* __restrict__ ctx) {
  __shared__ float wredf[4][64];
  __shared__ int wredi[4][64];
  __shared__ float sM[64];
  __shared__ int s_dirty[64];
  __shared__ int s_nm;
  __shared__ float sfb[NN];
  __shared__ float fred[256];
  __shared__ int ired[256];
  __shared__ int8_t pq[NN];

  const int t = threadIdx.x;
  const int hb = blockIdx.x, b = hb >> 4, h = hb & 15;
  const int q0 = blockIdx.y * 64;
  const int wid = t >> 6, lane = t & 63;
  const int l15 = lane & 15, l4 = lane >> 4;

  if (t == 0) s_nm = 1;
  __syncthreads();
  if (t < 64 && flags[b * NN + q0 + t] == 0) s_nm = 0;
  __syncthreads();
  const bool nomask = (s_nm != 0);

  const int8_t* Qh = Q + (size_t)hb * NN * NHD;
  const int8_t* Kh = K + (size_t)hb * NN * NHD;

  // 4 loop-invariant Q B-frags (verified layout: col=l&15, k=(l>>4)*16)
  int32x4 qf0 = *(const int32x4*)(Qh + (size_t)(q0 + l15) * NHD + l4 * 16);
  int32x4 qf1 = *(const int32x4*)(Qh + (size_t)(q0 + 16 + l15) * NHD + l4 * 16);
  int32x4 qf2 = *(const int32x4*)(Qh + (size_t)(q0 + 32 + l15) * NHD + l4 * 16);
  int32x4 qf3 = *(const int32x4*)(Qh + (size_t)(q0 + 48 + l15) * NHD + l4 * 16);

  const float* mr0 = mask + ((size_t)(b * NN + q0 + l15)) * NN;
  const float* mr1 = mr0 + (size_t)16 * NN;
  const float* mr2 = mr0 + (size_t)32 * NN;
  const float* mr3 = mr0 + (size_t)48 * NN;
  const int kwbase = wid * 512;
  const int32x4 z4 = {0, 0, 0, 0};

#define KFRAG(kt) (*(const int32x4*)(Kh + (size_t)(kwbase + (kt) * 16 + l15) * NHD + l4 * 16))

  if (nomask) {
    // ---- single fused pass with K prefetch ----
    int im0 = INT_MIN, im1 = INT_MIN, im2 = INT_MIN, im3 = INT_MIN;
    float sa0 = 0.f, sb0 = 0.f, sa1 = 0.f, sb1 = 0.f;
    float sa2 = 0.f, sb2 = 0.f, sa3 = 0.f, sb3 = 0.f;
    int32x4 a = KFRAG(0);
    for (int kt = 0; kt < 32; ++kt) {
      const int32x4 an = KFRAG(kt == 31 ? 31 : kt + 1);  // prefetch
      const int32x4 c0 = __builtin_amdgcn_mfma_i32_16x16x64_i8(a, qf0, z4, 0, 0, 0);
      const int32x4 c1 = __builtin_amdgcn_mfma_i32_16x16x64_i8(a, qf1, z4, 0, 0, 0);
      const int32x4 c2 = __builtin_amdgcn_mfma_i32_16x16x64_i8(a, qf2, z4, 0, 0, 0);
      const int32x4 c3 = __builtin_amdgcn_mfma_i32_16x16x64_i8(a, qf3, z4, 0, 0, 0);
#pragma unroll
      for (int r = 0; r < 4; ++r) {
        im0 = max(im0, c0[r]); im1 = max(im1, c1[r]);
        im2 = max(im2, c2[r]); im3 = max(im3, c3[r]);
      }
      sa0 += EXP2F((float)c0[0] * C2) + EXP2F((float)c0[1] * C2);
      sb0 += EXP2F((float)c0[2] * C2) + EXP2F((float)c0[3] * C2);
      sa1 += EXP2F((float)c1[0] * C2) + EXP2F((float)c1[1] * C2);
      sb1 += EXP2F((float)c1[2] * C2) + EXP2F((float)c1[3] * C2);
      sa2 += EXP2F((float)c2[0] * C2) + EXP2F((float)c2[1] * C2);
      sb2 += EXP2F((float)c2[2] * C2) + EXP2F((float)c2[3] * C2);
      sa3 += EXP2F((float)c3[0] * C2) + EXP2F((float)c3[1] * C2);
      sb3 += EXP2F((float)c3[2] * C2) + EXP2F((float)c3[3] * C2);
      a = an;
    }
    float s0 = sa0 + sb0, s1 = sa1 + sb1, s2 = sa2 + sb2, s3 = sa3 + sb3;
#pragma unroll
    for (int off = 16; off <= 32; off <<= 1) {
      im0 = max(im0, __shfl_xor(im0, off)); s0 += __shfl_xor(s0, off);
      im1 = max(im1, __shfl_xor(im1, off)); s1 += __shfl_xor(s1, off);
      im2 = max(im2, __shfl_xor(im2, off)); s2 += __shfl_xor(s2, off);
      im3 = max(im3, __shfl_xor(im3, off)); s3 += __shfl_xor(s3, off);
    }
    if (lane < 16) {
      wredi[wid][lane] = im0;      wredf[wid][lane] = s0;
      wredi[wid][16 + lane] = im1; wredf[wid][16 + lane] = s1;
      wredi[wid][32 + lane] = im2; wredf[wid][32 + lane] = s2;
      wredi[wid][48 + lane] = im3; wredf[wid][48 + lane] = s3;
    }
    __syncthreads();
    if (t < 64) {
      int M = wredi[0][t];
      float S = wredf[0][t];
#pragma unroll
      for (int w2 = 1; w2 < 4; ++w2) {
        M = max(M, wredi[w2][t]);
        S += wredf[w2][t];
      }
      float lb = (M > 61440 || M < -61440) ? 0.f : S * EXP2F(-(float)M * C2);
      s_dirty[t] = (lb >= 96.f) ? 0 : 1;   // NaN -> dirty
    }
    __syncthreads();
  } else {
    // ---- masked: two-pass float path ----
    float m0 = -FLT_MAX, m1 = -FLT_MAX, m2 = -FLT_MAX, m3 = -FLT_MAX;
    for (int kt = 0; kt < 32; ++kt) {
      const int32x4 a = KFRAG(kt);
      const int32x4 c0 = __builtin_amdgcn_mfma_i32_16x16x64_i8(a, qf0, z4, 0, 0, 0);
      const int32x4 c1 = __builtin_amdgcn_mfma_i32_16x16x64_i8(a, qf1, z4, 0, 0, 0);
      const int32x4 c2 = __builtin_amdgcn_mfma_i32_16x16x64_i8(a, qf2, z4, 0, 0, 0);
      const int32x4 c3 = __builtin_amdgcn_mfma_i32_16x16x64_i8(a, qf3, z4, 0, 0, 0);
      const int kofs = kwbase + kt * 16 + l4 * 4;
#pragma unroll
      for (int r = 0; r < 4; ++r) {
        m0 = fmaxf(m0, fmaxf((float)c0[r] * (1.f / 1024.f) + mr0[kofs + r], -FLT_MAX));
        m1 = fmaxf(m1, fmaxf((float)c1[r] * (1.f / 1024.f) + mr1[kofs + r], -FLT_MAX));
        m2 = fmaxf(m2, fmaxf((float)c2[r] * (1.f / 1024.f) + mr2[kofs + r], -FLT_MAX));
        m3 = fmaxf(m3, fmaxf((float)c3[r] * (1.f / 1024.f) + mr3[kofs + r], -FLT_MAX));
      }
    }
#pragma unroll
    for (int off = 16; off <= 32; off <<= 1) {
      m0 = fmaxf(m0, __shfl_xor(m0, off));
      m1 = fmaxf(m1, __shfl_xor(m1, off));
      m2 = fmaxf(m2, __shfl_xor(m2, off));
      m3 = fmaxf(m3, __shfl_xor(m3, off));
    }
    if (lane < 16) {
      wredf[wid][lane] = m0;      wredf[wid][16 + lane] = m1;
      wredf[wid][32 + lane] = m2; wredf[wid][48 + lane] = m3;
    }
    __syncthreads();
    if (t < 64) {
      float M = wredf[0][t];
#pragma unroll
      for (int w2 = 1; w2 < 4; ++w2) M = fmaxf(M, wredf[w2][t]);
      sM[t] = M;
    }
    __syncthreads();
    const float M0 = sM[l15], M1 = sM[16 + l15];
    const float M2 = sM[32 + l15], M3 = sM[48 + l15];
    float s0 = 0.f, s1 = 0.f, s2 = 0.f, s3 = 0.f;
    for (int kt = 0; kt < 32; ++kt) {
      const int32x4 a = KFRAG(kt);
      const int32x4 c0 = __builtin_amdgcn_mfma_i32_16x16x64_i8(a, qf0, z4, 0, 0, 0);
      const int32x4 c1 = __builtin_amdgcn_mfma_i32_16x16x64_i8(a, qf1, z4, 0, 0, 0);
      const int32x4 c2 = __builtin_amdgcn_mfma_i32_16x16x64_i8(a, qf2, z4, 0, 0, 0);
      const int32x4 c3 = __builtin_amdgcn_mfma_i32_16x16x64_i8(a, qf3, z4, 0, 0, 0);
      const int kofs = kwbase + kt * 16 + l4 * 4;
#pragma unroll
      for (int r = 0; r < 4; ++r) {
        s0 += __expf(fmaxf((float)c0[r] * (1.f / 1024.f) + mr0[kofs + r], -FLT_MAX) - M0);
        s1 += __expf(fmaxf((float)c1[r] * (1.f / 1024.f) + mr1[kofs + r], -FLT_MAX) - M1);
        s2 += __expf(fmaxf((float)c2[r] * (1.f / 1024.f) + mr2[kofs + r], -FLT_MAX) - M2);
        s3 += __expf(fmaxf((float)c3[r] * (1.f / 1024.f) + mr3[kofs + r], -FLT_MAX) - M3);
      }
    }
#pragma unroll
    for (int off = 16; off <= 32; off <<= 1) {
      s0 += __shfl_xor(s0, off); s1 += __shfl_xor(s1, off);
      s2 += __shfl_xor(s2, off); s3 += __shfl_xor(s3, off);
    }
    if (lane < 16) {
      wredf[wid][lane] = s0;      wredf[wid][16 + lane] = s1;
      wredf[wid][32 + lane] = s2; wredf[wid][48 + lane] = s3;
    }
    __syncthreads();
    if (t < 64) {
      const float S = wredf[0][t] + wredf[1][t] + wredf[2][t] + wredf[3][t];
      s_dirty[t] = (S >= 96.f) ? 0 : 1;
    }
    __syncthreads();
  }
#undef KFRAG

  // clean rows: ctx exactly zero (4 threads per row, 2 x int4 each)
  {
    const int rl = t >> 2;
    if (!s_dirty[rl]) {
      int4* p = (int4*)(ctx + ((size_t)(b * NN + q0 + rl)) * ND + h * NHD);
      const int4 z = {0, 0, 0, 0};
      p[(t & 3) * 2] = z;
      p[(t & 3) * 2 + 1] = z;
    }
  }

  // dirty rows: exact fallback (rare; fully honest path)
  for (int rl = 0; rl < 64; ++rl) {
    if (!s_dirty[rl]) continue;
    __syncthreads();
    const int qrow = q0 + rl;
    const int* Qr = (const int*)(Qh + (size_t)qrow * NHD);
    const float* mrow = mask + ((size_t)(b * NN + qrow)) * NN;
    int qreg[16];
#pragma unroll
    for (int i = 0; i < 16; ++i) qreg[i] = Qr[i];
#pragma unroll
    for (int jj = 0; jj < 8; ++jj) {
      const int j = jj * 256 + t;
      const int* Kj = (const int*)(Kh + (size_t)j * NHD);
      int acc = 0;
#pragma unroll
      for (int i = 0; i < 16; ++i) acc = dot4(qreg[i], Kj[i], acc);
      sfb[j] = fmaxf((float)acc * (1.f / 1024.f) + mrow[j], -FLT_MAX);
    }
    __syncthreads();
    float lm = -INFINITY;
#pragma unroll
    for (int jj = 0; jj < 8; ++jj) lm = fmaxf(lm, sfb[jj * 256 + t]);
    fred[t] = lm;
    __syncthreads();
    for (int off = 128; off; off >>= 1) {
      if (t < off) fred[t] = fmaxf(fred[t], fred[t + off]);
      __syncthreads();
    }
    const float M = fred[0];
    __syncthreads();
    float ls = 0.f;
#pragma unroll
    for (int jj = 0; jj < 8; ++jj) {
      const int j = jj * 256 + t;
      const float e = expf(sfb[j] - M);
      sfb[j] = e; ls += e;
    }
    fred[t] = ls;
    __syncthreads();
    for (int off = 128; off; off >>= 1) {
      if (t < off) fred[t] += fred[t + off];
      __syncthreads();
    }
    const float S = fred[0];
#pragma unroll
    for (int jj = 0; jj < 8; ++jj) {
      const int j = jj * 256 + t;
      const int pi = (int)rintf(sfb[j] / S * 32.f);
      pq[j] = (int8_t)min(127, pi);
    }
    __syncthreads();
    const int8_t* Vh = V + (size_t)hb * NN * NHD;
    const int d = t & 63, ch = t >> 6;
    int a = 0;
    for (int j = ch * 512; j < ch * 512 + 512; ++j) {
      const int pv = pq[j];
      if (pv) a += pv * (int)Vh[(size_t)j * NHD + d];
    }
    ired[t] = a;
    __syncthreads();
    if (t < 64) {
      const int tot = ired[t] + ired[t + 64] + ired[t + 128] + ired[t + 192];
      ctx[((size_t)(b * NN + qrow)) * ND + h * NHD + t] =
          (int8_t)clampq((int)rintf((float)tot * (1.f / 32.f)));
    }
    __syncthreads();
  }
}

extern "C" void kernel_launch(void* const* d_in, const int* in_sizes, int n_in,
                              void* d_out, int out_size, void* d_ws, size_t ws_size,
                              hipStream_t stream) {
  float* out = (float*)d_out;

  if (ws_size < (size_t)WS_NEEDED) {
    zero_out_k<<<out_size / 1024, 256, 0, stream>>>((float4*)out);
    return;
  }

  const float* hidden = (const float*)d_in[0];
  const float* mask   = (const float*)d_in[1];
  const float* qw = (const float*)d_in[2];
  const float* qb = (const float*)d_in[3];
  const float* kw = (const float*)d_in[4];
  const float* kb = (const float*)d_in[5];
  const float* vw = (const float*)d_in[6];
  const float* vb = (const float*)d_in[7];
  const float* ow = (const float*)d_in[8];
  const float* ob = (const float*)d_in[9];

  char* ws = (char*)d_ws;
  int8_t* x_i8  = (int8_t*)(ws + 0);          // 4 MiB [4096][1024]
  int8_t* qw_i8 = (int8_t*)(ws + 4194304);
  int8_t* kw_i8 = (int8_t*)(ws + 5242880);
  int8_t* vw_i8 = (int8_t*)(ws + 6291456);
  int8_t* ow_i8 = (int8_t*)(ws + 7340032);
  int8_t* qb_i8 = (int8_t*)(ws + 8388608);
  int8_t* kb_i8 = (int8_t*)(ws + 8389632);
  int8_t* vb_i8 = (int8_t*)(ws + 8390656);
  int8_t* ob_i8 = (int8_t*)(ws + 8391680);
  int8_t* Q_i8  = (int8_t*)(ws + 8392704);    // 4 MiB [32][2048][64]
  int8_t* K_i8  = (int8_t*)(ws + 12587008);   // 4 MiB
  int8_t* V_i8  = (int8_t*)(ws + 16781312);   // 4 MiB
  int8_t* c_i8  = (int8_t*)(ws + 20975616);   // 4 MiB [4096][1024]
  int* mflags   = (int*)(ws + 25169920);      // 16 KiB (no aliasing)

  // 1) quantize everything + mask flags in one launch
  quant_all_k<<<12292, 256, 0, stream>>>(hidden, qw, kw, vw, ow, qb, kb, vb, ob,
                                         mask, (int*)x_i8, (int*)qw_i8,
                                         (int*)kw_i8, (int*)vw_i8, (int*)ow_i8,
                                         (int*)qb_i8, (int*)kb_i8, (int*)vb_i8,
                                         (int*)ob_i8, mflags);

  // 2) fused QKV projection (grid.z picks head), dbuf 2-phase K-loop
  gemm_qkv_k<<<dim3(ND / BN, NB * NN / BM, 3), 256, 0, stream>>>(
      x_i8, qw_i8, kw_i8, vw_i8, qb_i8, kb_i8, vb_i8, Q_i8, K_i8, V_i8);

  // 3) attention (64 q-rows/block, prefetched K, certificate + exact fallback)
  attn_k<<<dim3(NHB, NN / 64), 256, 0, stream>>>(Q_i8, K_i8, V_i8, mask, mflags, c_i8);

  // 4) output projection -> f32
  gemm_o_k<<<dim3(ND / BN, NB * NN / BM), 256, 0, stream>>>(c_i8, ow_i8, ob_i8, out);
}

// Round 11
// 171.332 us; speedup vs baseline: 15.2969x; 1.0728x over previous
//
#include <hip/hip_runtime.h>
#include <cstdint>
#include <cfloat>
#include <climits>

// Problem constants (B=2, N=2048, D=1024, H=16, HD=64)
#define NB 2
#define NN 2048
#define ND 1024
#define NH 16
#define NHD 64
#define NHB (NB*NH)   // 32
#define WS_NEEDED 25202688u   // buffers + mask flags + row flags (ws is 256 MiB)

#if defined(__has_builtin)
#if __has_builtin(__builtin_amdgcn_sdot4)
#define HAS_SDOT4 1
#endif
#endif

typedef __attribute__((ext_vector_type(4))) int int32x4;

__device__ __forceinline__ int dot4(int a, int b, int acc) {
#if defined(HAS_SDOT4)
  return __builtin_amdgcn_sdot4(a, b, acc, false);
#else
  acc += (int)(int8_t)(a & 255)       * (int)(int8_t)(b & 255);
  acc += (int)(int8_t)((a >> 8) & 255) * (int)(int8_t)((b >> 8) & 255);
  acc += (int)(int8_t)((a >> 16) & 255)* (int)(int8_t)((b >> 16) & 255);
  acc += (int)(int8_t)(a >> 24)        * (int)(int8_t)(b >> 24);
  return acc;
#endif
}

__device__ __forceinline__ int clampq(int v) {
  return min(127, max(-128, v));
}

__global__ __launch_bounds__(256) void zero_out_k(float4* __restrict__ out) {
  out[blockIdx.x * 256 + threadIdx.x] = float4{0.f, 0.f, 0.f, 0.f};
}

__device__ __forceinline__ int quant4(float4 f) {
  int a = clampq((int)rintf(f.x * 32.f));
  int b = clampq((int)rintf(f.y * 32.f));
  int c = clampq((int)rintf(f.z * 32.f));
  int d = clampq((int)rintf(f.w * 32.f));
  return (a & 255) | ((b & 255) << 8) | ((c & 255) << 16) | (d << 24);
}

// one launch: hidden (0..4095), weights (4096..8191), biases (8192..8195),
// mask all-zero row flags (8196..12291), rflags zero-init (12292)
__global__ __launch_bounds__(256) void quant_all_k(
    const float* __restrict__ hidden, const float* __restrict__ qw,
    const float* __restrict__ kw, const float* __restrict__ vw,
    const float* __restrict__ ow, const float* __restrict__ qb,
    const float* __restrict__ kb, const float* __restrict__ vb,
    const float* __restrict__ ob, const float* __restrict__ mask,
    int* __restrict__ xo, int* __restrict__ qwo, int* __restrict__ kwo,
    int* __restrict__ vwo, int* __restrict__ owo, int* __restrict__ qbo,
    int* __restrict__ kbo, int* __restrict__ vbo, int* __restrict__ obo,
    int* __restrict__ mflags, int* __restrict__ rflags) {
  __shared__ int red[256];
  const int bid = blockIdx.x;
  const int t = threadIdx.x;
  if (bid < 4096) {
    const int i = bid * 256 + t;
    xo[i] = quant4(reinterpret_cast<const float4*>(hidden)[i]);
  } else if (bid < 8192) {
    const int wb = bid - 4096;
    const int which = wb >> 10;
    const float* src = which == 0 ? qw : which == 1 ? kw : which == 2 ? vw : ow;
    int* dst = which == 0 ? qwo : which == 1 ? kwo : which == 2 ? vwo : owo;
    const int i = (wb & 1023) * 256 + t;
    dst[i] = quant4(reinterpret_cast<const float4*>(src)[i]);
  } else if (bid < 8196) {
    const int which = bid - 8192;
    const float* src = which == 0 ? qb : which == 1 ? kb : which == 2 ? vb : ob;
    int* dst = which == 0 ? qbo : which == 1 ? kbo : which == 2 ? vbo : obo;
    dst[t] = quant4(reinterpret_cast<const float4*>(src)[t]);
  } else if (bid < 12292) {
    const int row = bid - 8196;   // 0..4095 = b*2048 + r
    const float4* mr = (const float4*)(mask + (size_t)row * NN);
    int nz = 0;
#pragma unroll
    for (int i = 0; i < 2; ++i) {
      float4 f = mr[t * 2 + i];
      nz |= (f.x != 0.f) | (f.y != 0.f) | (f.z != 0.f) | (f.w != 0.f);
    }
    red[t] = nz;
    __syncthreads();
    for (int off = 128; off; off >>= 1) {
      if (t < off) red[t] |= red[t + off];
      __syncthreads();
    }
    if (t == 0) mflags[row] = (red[0] == 0);
  } else {
    // zero-init per-row dirty flags (16 ints per thread)
#pragma unroll
    for (int i = 0; i < 16; ++i) rflags[t * 16 + i] = 0;
  }
}

// ---------------------------------------------------------------------------
// MFMA i8 GEMM, double-buffered 2-phase K-loop (verified bit-exact r8-r9).
// ---------------------------------------------------------------------------
#define BM 64
#define BN 128
#define BK 64

template <bool OPROJ>
__device__ __forceinline__ void gemm_body(const int8_t* __restrict__ x,
                                          const int8_t* __restrict__ w,
                                          const int8_t* __restrict__ bq,
                                          int8_t* __restrict__ outq,
                                          float* __restrict__ outf,
                                          float scale) {
  __shared__ __align__(16) int8_t lA[2][BM * BK];  // 2 x 4 KiB
  __shared__ __align__(16) int8_t lB[2][BN * BK];  // 2 x 8 KiB
  const int t = threadIdx.x;
  const int wid = t >> 6;
  const int lane = t & 63;
  const int wr = wid >> 1, wc = wid & 1;
  const int bm = blockIdx.y * BM;
  const int bn = blockIdx.x * BN;

  const int srow = lane >> 2;          // staging: lane -> row srow, byte scol
  const int scol = (lane & 3) * 16;    // (lane*16 == srow*64 + scol)
  const int frow = lane & 15;          // fragment: row lane&15, k (lane>>4)*16
  const int fk = (lane >> 4) * 16;

  const int8_t* gxa = x + (size_t)(bm + wid * 16 + srow) * ND + scol;
  const int8_t* gwb0 = w + (size_t)(bn + wid * 16 + srow) * ND + scol;
  const int8_t* gwb1 = w + (size_t)(bn + (wid + 4) * 16 + srow) * ND + scol;

#define STAGE(buf, ks)                                                          \
  do {                                                                          \
    const int k0_ = (ks) * BK;                                                  \
    __builtin_amdgcn_global_load_lds(                                           \
        (const __attribute__((address_space(1))) void*)(gxa + k0_),             \
        (__attribute__((address_space(3))) void*)(lA[buf] + wid * 1024), 16, 0, 0); \
    __builtin_amdgcn_global_load_lds(                                           \
        (const __attribute__((address_space(1))) void*)(gwb0 + k0_),            \
        (__attribute__((address_space(3))) void*)(lB[buf] + wid * 1024), 16, 0, 0); \
    __builtin_amdgcn_global_load_lds(                                           \
        (const __attribute__((address_space(1))) void*)(gwb1 + k0_),            \
        (__attribute__((address_space(3))) void*)(lB[buf] + (wid + 4) * 1024), 16, 0, 0); \
  } while (0)

  int32x4 acc[2][4];
#pragma unroll
  for (int i = 0; i < 2; ++i)
#pragma unroll
    for (int j = 0; j < 4; ++j) acc[i][j] = int32x4{0, 0, 0, 0};

  STAGE(0, 0);
  __syncthreads();  // drains vmcnt: buf0 ready

  for (int ks = 0; ks < ND / BK; ++ks) {
    const int cur = ks & 1;
    if (ks + 1 < ND / BK) STAGE(cur ^ 1, ks + 1);  // loads fly under compute

    int32x4 af[2], bf[4];
#pragma unroll
    for (int mi = 0; mi < 2; ++mi)
      af[mi] = *(const int32x4*)(lA[cur] + (wr * 32 + mi * 16 + frow) * BK + fk);
#pragma unroll
    for (int ni = 0; ni < 4; ++ni)
      bf[ni] = *(const int32x4*)(lB[cur] + (wc * 64 + ni * 16 + frow) * BK + fk);
#pragma unroll
    for (int mi = 0; mi < 2; ++mi)
#pragma unroll
      for (int ni = 0; ni < 4; ++ni)
        acc[mi][ni] = __builtin_amdgcn_mfma_i32_16x16x64_i8(af[mi], bf[ni],
                                                            acc[mi][ni], 0, 0, 0);
    __syncthreads();
  }
#undef STAGE

  const int crow = (lane >> 4) * 4;   // C/D map: col=lane&15, row=(lane>>4)*4+reg
  const int ccol = lane & 15;
#pragma unroll
  for (int ni = 0; ni < 4; ++ni) {
    const int n = bn + wc * 64 + ni * 16 + ccol;
    const float bqf = (float)bq[n] * (1.f / 32.f);
    const int h = n >> 6, hd = n & 63;
#pragma unroll
    for (int mi = 0; mi < 2; ++mi) {
#pragma unroll
      for (int r = 0; r < 4; ++r) {
        const int m = bm + wr * 32 + mi * 16 + crow + r;
        const float val = (float)acc[mi][ni][r] * (1.f / 1024.f) + bqf;
        if (OPROJ) {
          outf[(size_t)m * ND + n] = val;
        } else {
          const int qv = clampq((int)rintf(val * scale * 32.f));
          const int b_ = m >> 11, nr = m & 2047;
          outq[(((size_t)((b_ << 4) + h) << 11) + nr) * NHD + hd] = (int8_t)qv;
        }
      }
    }
  }
}

__global__ __launch_bounds__(256) void gemm_qkv_k(const int8_t* __restrict__ x,
                                                  const int8_t* __restrict__ wq,
                                                  const int8_t* __restrict__ wk,
                                                  const int8_t* __restrict__ wv,
                                                  const int8_t* __restrict__ bqq,
                                                  const int8_t* __restrict__ bqk,
                                                  const int8_t* __restrict__ bqv,
                                                  int8_t* __restrict__ oq,
                                                  int8_t* __restrict__ ok,
                                                  int8_t* __restrict__ ov) {
  const int z = blockIdx.z;
  const int8_t* w = z == 0 ? wq : z == 1 ? wk : wv;
  const int8_t* bq = z == 0 ? bqq : z == 1 ? bqk : bqv;
  int8_t* out = z == 0 ? oq : z == 1 ? ok : ov;
  const float scale = z == 0 ? 0.125f : 1.0f;
  gemm_body<false>(x, w, bq, out, nullptr, scale);
}

// oproj with all-clean early-out: clean rows' output is exactly bq/32
__global__ __launch_bounds__(256) void gemm_o_k(const int8_t* __restrict__ x,
                                                const int8_t* __restrict__ w,
                                                const int8_t* __restrict__ bq,
                                                const int* __restrict__ rflags,
                                                float* __restrict__ out) {
  __shared__ int s_any;
  const int t = threadIdx.x;
  const int bm = blockIdx.y * BM;
  const int bn = blockIdx.x * BN;
  if (t == 0) s_any = 0;
  __syncthreads();
  if (t < 64 && rflags[bm + t] != 0) s_any = 1;
  __syncthreads();
  if (s_any == 0) {
    // all 64 rows clean: out = bq/32 (exact; ctx rows are all zero)
    const int m = bm + (t >> 2);
    const int n0 = bn + (t & 3) * 32;
    float4* po = (float4*)(out + (size_t)m * ND + n0);
#pragma unroll
    for (int j = 0; j < 8; ++j) {
      float4 v;
      v.x = (float)bq[n0 + j * 4 + 0] * (1.f / 32.f);
      v.y = (float)bq[n0 + j * 4 + 1] * (1.f / 32.f);
      v.z = (float)bq[n0 + j * 4 + 2] * (1.f / 32.f);
      v.w = (float)bq[n0 + j * 4 + 3] * (1.f / 32.f);
      po[j] = v;
    }
    return;
  }
  gemm_body<true>(x, w, bq, nullptr, out, 1.0f);
}

// ---------------------------------------------------------------------------
// Attention with Jensen certificate. Per 64 q-rows of one (b,h):
//  prologue: Ksum[d] = sum_k K[k][d]; qdK[r] = q_r . Ksum  (int64, exact)
//  main: int row-max M over MFMA accs (1 VALU op/score, no float)
//  clean iff mask row all-zero AND 2048*M - qdK <= 3400*2048  (int64 compare)
//    [Jensen: S >= 2048*exp(mu) -> p_max <= exp((M-mu*2048... )/1024)/2048;
//     at 3400: 32*p_max <= 0.433 < 0.5; true cutoff 2048*1024*ln32 = 7270953]
//  clean rows: ctx segment = 0 (exact). dirty rows: exact fallback (honest
//  scores+mask+softmax+quantized PV). rflags OR-merged across heads for oproj.
// ---------------------------------------------------------------------------
__global__ __launch_bounds__(256) void attn_k(const int8_t* __restrict__ Q,
                                              const int8_t* __restrict__ K,
                                              const int8_t* __restrict__ V,
                                              const float* __restrict__ mask,
                                              const int* __restrict__ mflags,
                                              int8_t* __restrict__ ctx,
                                              int* __restrict__ rflags) {
  __shared__ __align__(16) char pool[16384];   // part[64][64] / fallback arrays
  __shared__ int sKsum[64];
  __shared__ long long sQdK[64];
  __shared__ int wredi[4][64];
  __shared__ int s_dirty[64];

  const int t = threadIdx.x;
  const int hb = blockIdx.x, b = hb >> 4, h = hb & 15;
  const int q0 = blockIdx.y * 64;
  const int wid = t >> 6, lane = t & 63;
  const int l15 = lane & 15, l4 = lane >> 4;

  const int8_t* Qh = Q + (size_t)hb * NN * NHD;
  const int8_t* Kh = K + (size_t)hb * NN * NHD;
  const int8_t* Vh = V + (size_t)hb * NN * NHD;

  // ---- prologue: Ksum ----
  {
    int (*part)[64] = (int(*)[64])pool;
    const int rgrp = t >> 2, sl = t & 3;
    int a[16];
#pragma unroll
    for (int j = 0; j < 16; ++j) a[j] = 0;
    for (int i = 0; i < 32; ++i) {
      const int row = rgrp + (i << 6);
      const int4 v = *(const int4*)(Kh + (size_t)row * NHD + sl * 16);
      const int vv[4] = {v.x, v.y, v.z, v.w};
#pragma unroll
      for (int c = 0; c < 4; ++c) {
        a[c * 4 + 0] += (int)(int8_t)(vv[c] & 255);
        a[c * 4 + 1] += (int)(int8_t)((vv[c] >> 8) & 255);
        a[c * 4 + 2] += (int)(int8_t)((vv[c] >> 16) & 255);
        a[c * 4 + 3] += (int)(int8_t)(vv[c] >> 24);
      }
    }
#pragma unroll
    for (int j = 0; j < 16; ++j) part[rgrp][sl * 16 + j] = a[j];
    __syncthreads();
    if (t < 64) {
      int s = 0;
#pragma unroll 8
      for (int rg = 0; rg < 64; ++rg) s += part[rg][t];
      sKsum[t] = s;
    }
    __syncthreads();
  }

  // ---- qdK per row (int64 exact) ----
  if (t < 64) {
    const int8_t* qr = Qh + (size_t)(q0 + t) * NHD;
    long long s = 0;
#pragma unroll 16
    for (int d = 0; d < 64; ++d) s += (long long)qr[d] * (long long)sKsum[d];
    sQdK[t] = s;
  }

  // ---- main loop: int row max over QK^T accs ----
  const int32x4 qf0 = *(const int32x4*)(Qh + (size_t)(q0 + l15) * NHD + l4 * 16);
  const int32x4 qf1 = *(const int32x4*)(Qh + (size_t)(q0 + 16 + l15) * NHD + l4 * 16);
  const int32x4 qf2 = *(const int32x4*)(Qh + (size_t)(q0 + 32 + l15) * NHD + l4 * 16);
  const int32x4 qf3 = *(const int32x4*)(Qh + (size_t)(q0 + 48 + l15) * NHD + l4 * 16);
  const int kwbase = wid * 512;
  const int32x4 z4 = {0, 0, 0, 0};
#define KFRAG(kt) (*(const int32x4*)(Kh + (size_t)(kwbase + (kt) * 16 + l15) * NHD + l4 * 16))

  int im0 = INT_MIN, im1 = INT_MIN, im2 = INT_MIN, im3 = INT_MIN;
  {
    int32x4 a = KFRAG(0);
    for (int kt = 0; kt < 32; ++kt) {
      const int32x4 an = KFRAG(kt == 31 ? 31 : kt + 1);
      const int32x4 c0 = __builtin_amdgcn_mfma_i32_16x16x64_i8(a, qf0, z4, 0, 0, 0);
      const int32x4 c1 = __builtin_amdgcn_mfma_i32_16x16x64_i8(a, qf1, z4, 0, 0, 0);
      const int32x4 c2 = __builtin_amdgcn_mfma_i32_16x16x64_i8(a, qf2, z4, 0, 0, 0);
      const int32x4 c3 = __builtin_amdgcn_mfma_i32_16x16x64_i8(a, qf3, z4, 0, 0, 0);
      im0 = max(im0, max(max(c0[0], c0[1]), max(c0[2], c0[3])));
      im1 = max(im1, max(max(c1[0], c1[1]), max(c1[2], c1[3])));
      im2 = max(im2, max(max(c2[0], c2[1]), max(c2[2], c2[3])));
      im3 = max(im3, max(max(c3[0], c3[1]), max(c3[2], c3[3])));
      a = an;
    }
  }
#undef KFRAG
#pragma unroll
  for (int off = 16; off <= 32; off <<= 1) {
    im0 = max(im0, __shfl_xor(im0, off));
    im1 = max(im1, __shfl_xor(im1, off));
    im2 = max(im2, __shfl_xor(im2, off));
    im3 = max(im3, __shfl_xor(im3, off));
  }
  if (lane < 16) {
    wredi[wid][lane] = im0;      wredi[wid][16 + lane] = im1;
    wredi[wid][32 + lane] = im2; wredi[wid][48 + lane] = im3;
  }
  __syncthreads();

  // ---- decision + rflags ----
  if (t < 64) {
    int M = wredi[0][t];
#pragma unroll
    for (int w2 = 1; w2 < 4; ++w2) M = max(M, wredi[w2][t]);
    const int gr = b * NN + q0 + t;
    const bool ok = (mflags[gr] != 0) &&
                    ((long long)M * 2048LL - sQdK[t] <= 6963200LL);
    s_dirty[t] = ok ? 0 : 1;
    if (!ok) atomicOr(&rflags[gr], 1);
  }
  __syncthreads();

  // ---- clean rows: ctx segment exactly zero (64 B per row) ----
  {
    const int rl = t >> 2;
    if (!s_dirty[rl]) {
      int4* p = (int4*)(ctx + ((size_t)(b * NN + q0 + rl)) * ND + h * NHD);
      const int4 z = {0, 0, 0, 0};
      p[t & 3] = z;
    }
  }

  // ---- dirty rows: exact fallback ----
  float* sfb = (float*)pool;                 // 8 KiB
  int8_t* pq = (int8_t*)(pool + 8192);       // 2 KiB
  float* fred = (float*)(pool + 10240);      // 1 KiB
  int* ired = (int*)(pool + 11264);          // 1 KiB
  for (int rl = 0; rl < 64; ++rl) {
    if (!s_dirty[rl]) continue;
    __syncthreads();
    const int qrow = q0 + rl;
    const int* Qr = (const int*)(Qh + (size_t)qrow * NHD);
    const float* mrow = mask + ((size_t)(b * NN + qrow)) * NN;
    int qreg[16];
#pragma unroll
    for (int i = 0; i < 16; ++i) qreg[i] = Qr[i];
#pragma unroll
    for (int jj = 0; jj < 8; ++jj) {
      const int j = jj * 256 + t;
      const int* Kj = (const int*)(Kh + (size_t)j * NHD);
      int acc = 0;
#pragma unroll
      for (int i = 0; i < 16; ++i) acc = dot4(qreg[i], Kj[i], acc);
      sfb[j] = fmaxf((float)acc * (1.f / 1024.f) + mrow[j], -FLT_MAX);
    }
    __syncthreads();
    float lm = -INFINITY;
#pragma unroll
    for (int jj = 0; jj < 8; ++jj) lm = fmaxf(lm, sfb[jj * 256 + t]);
    fred[t] = lm;
    __syncthreads();
    for (int off = 128; off; off >>= 1) {
      if (t < off) fred[t] = fmaxf(fred[t], fred[t + off]);
      __syncthreads();
    }
    const float M = fred[0];
    __syncthreads();
    float ls = 0.f;
#pragma unroll
    for (int jj = 0; jj < 8; ++jj) {
      const int j = jj * 256 + t;
      const float e = expf(sfb[j] - M);
      sfb[j] = e; ls += e;
    }
    fred[t] = ls;
    __syncthreads();
    for (int off = 128; off; off >>= 1) {
      if (t < off) fred[t] += fred[t + off];
      __syncthreads();
    }
    const float S = fred[0];
#pragma unroll
    for (int jj = 0; jj < 8; ++jj) {
      const int j = jj * 256 + t;
      const int pi = (int)rintf(sfb[j] / S * 32.f);
      pq[j] = (int8_t)min(127, pi);
    }
    __syncthreads();
    const int d = t & 63, ch = t >> 6;
    int a = 0;
    for (int j = ch * 512; j < ch * 512 + 512; ++j) {
      const int pv = pq[j];
      if (pv) a += pv * (int)Vh[(size_t)j * NHD + d];
    }
    ired[t] = a;
    __syncthreads();
    if (t < 64) {
      const int tot = ired[t] + ired[t + 64] + ired[t + 128] + ired[t + 192];
      ctx[((size_t)(b * NN + qrow)) * ND + h * NHD + t] =
          (int8_t)clampq((int)rintf((float)tot * (1.f / 32.f)));
    }
    __syncthreads();
  }
}

extern "C" void kernel_launch(void* const* d_in, const int* in_sizes, int n_in,
                              void* d_out, int out_size, void* d_ws, size_t ws_size,
                              hipStream_t stream) {
  float* out = (float*)d_out;

  if (ws_size < (size_t)WS_NEEDED) {
    zero_out_k<<<out_size / 1024, 256, 0, stream>>>((float4*)out);
    return;
  }

  const float* hidden = (const float*)d_in[0];
  const float* mask   = (const float*)d_in[1];
  const float* qw = (const float*)d_in[2];
  const float* qb = (const float*)d_in[3];
  const float* kw = (const float*)d_in[4];
  const float* kb = (const float*)d_in[5];
  const float* vw = (const float*)d_in[6];
  const float* vb = (const float*)d_in[7];
  const float* ow = (const float*)d_in[8];
  const float* ob = (const float*)d_in[9];

  char* ws = (char*)d_ws;
  int8_t* x_i8  = (int8_t*)(ws + 0);          // 4 MiB [4096][1024]
  int8_t* qw_i8 = (int8_t*)(ws + 4194304);
  int8_t* kw_i8 = (int8_t*)(ws + 5242880);
  int8_t* vw_i8 = (int8_t*)(ws + 6291456);
  int8_t* ow_i8 = (int8_t*)(ws + 7340032);
  int8_t* qb_i8 = (int8_t*)(ws + 8388608);
  int8_t* kb_i8 = (int8_t*)(ws + 8389632);
  int8_t* vb_i8 = (int8_t*)(ws + 8390656);
  int8_t* ob_i8 = (int8_t*)(ws + 8391680);
  int8_t* Q_i8  = (int8_t*)(ws + 8392704);    // 4 MiB [32][2048][64]
  int8_t* K_i8  = (int8_t*)(ws + 12587008);   // 4 MiB
  int8_t* V_i8  = (int8_t*)(ws + 16781312);   // 4 MiB
  int8_t* c_i8  = (int8_t*)(ws + 20975616);   // 4 MiB [4096][1024]
  int* mflags   = (int*)(ws + 25169920);      // 16 KiB
  int* rflags   = (int*)(ws + 25186304);      // 16 KiB

  // 1) quantize + mask flags + rflags zero-init, one launch
  quant_all_k<<<12293, 256, 0, stream>>>(hidden, qw, kw, vw, ow, qb, kb, vb, ob,
                                         mask, (int*)x_i8, (int*)qw_i8,
                                         (int*)kw_i8, (int*)vw_i8, (int*)ow_i8,
                                         (int*)qb_i8, (int*)kb_i8, (int*)vb_i8,
                                         (int*)ob_i8, mflags, rflags);

  // 2) fused QKV projection
  gemm_qkv_k<<<dim3(ND / BN, NB * NN / BM, 3), 256, 0, stream>>>(
      x_i8, qw_i8, kw_i8, vw_i8, qb_i8, kb_i8, vb_i8, Q_i8, K_i8, V_i8);

  // 3) attention (Jensen certificate + exact fallback)
  attn_k<<<dim3(NHB, NN / 64), 256, 0, stream>>>(Q_i8, K_i8, V_i8, mask, mflags,
                                                 c_i8, rflags);

  // 4) output projection (all-clean blocks short-circuit to bias write)
  gemm_o_k<<<dim3(ND / BN, NB * NN / BM), 256, 0, stream>>>(c_i8, ow_i8, ob_i8,
                                                            rflags, out);
}